// Round 6
// baseline (291.011 us; speedup 1.0000x reference)
//
#include <hip/hip_runtime.h>
#include <math.h>

#define NN 100000
#define NE 1600000
#define D 64
#define NQ (NE / 4)

#define NBD 196                     // dst buckets, width 512 (dst>>9)
#define NBS 391                     // src buckets, width 256 (src>>8)

#define KB 125                      // partition blocks
#define QPB (NQ / KB)               // 3200 int4 quads per block (exact)
#define CAPB 128                    // D-cell capacity, ints   (lambda 65.3, +7.7 sigma)
#define CAPS_PB 80                  // S-cell capacity, bytes  (lambda 32.7, +8.3 sigma)
#define PTB 512
#define TFB 196                     // transform blocks: 512 nodes each (196*512=100352)

typedef _Float16 h4v __attribute__((ext_vector_type(4)));
typedef _Float16 h8v __attribute__((ext_vector_type(8)));

// ================== tiled transform: out[64 nodes] = fp16(scale * (in @ W)) ==========
// Replaces the shuffle-matmul (16 ds_bpermute + 16 ds_read per node on the single LDS
// pipe = ~50us/layer chip-wide — the hidden floor of r0-r5's partition_tf1 kernel).
// Per wave per k: 2 ds_read_b128 (xT, XOR-swizzled) + 1 global dwordx4 (W via L1) +
// 32 FMA -> 4 LDS ops/node. fp32 math, k ascending — precision identical to before.
// Pair of waves per 64-node tile: half=0 computes cols 0..31, half=1 cols 32..63.
// xT layout: xT[k][m ^ (k&60)] — staging writes and compute reads both 2-way max.
__device__ __forceinline__ void tile_transform(
    const float* __restrict__ in, const float* __restrict__ W,
    const float* __restrict__ scale, _Float16* __restrict__ out,
    float* xT, int tileBase, int t)
{
    int pt = t & 127;                   // pair-local tid
    int lane = t & 63;
    int half = (t >> 6) & 1;
    // ---- stage x tile (128 threads): coalesced row loads, swizzled transposed writes
    {
        int c4 = (pt & 15) << 2;        // k base
        int r0 = pt >> 4;               // 0..7
#pragma unroll
        for (int p = 0; p < 8; ++p) {
            int r = r0 + (p << 3);      // node-in-tile 0..63
            int node = tileBase + r;
            int nl = node < NN ? node : NN - 1;
            float4 v = *(const float4*)(in + (size_t)nl * D + c4);
            int P = c4 & 60;            // (c4+i)&60 == c4 for i<4
            xT[(c4 + 0) * 64 + (r ^ P)] = v.x;
            xT[(c4 + 1) * 64 + (r ^ P)] = v.y;
            xT[(c4 + 2) * 64 + (r ^ P)] = v.z;
            xT[(c4 + 3) * 64 + (r ^ P)] = v.w;
        }
    }
    __syncthreads();
    // ---- compute: lane owns 8 nodes x 4 cols ----
    int mg = lane >> 3, ng = lane & 7;
    int m0 = mg << 3;
    int nc = (half << 5) + (ng << 2);
    float4 acc[8];
#pragma unroll
    for (int j = 0; j < 8; ++j) acc[j] = {0.f, 0.f, 0.f, 0.f};
#pragma unroll 16
    for (int k = 0; k < 64; ++k) {
        int P = k & 60;
        float4 xa = *(const float4*)(xT + k * 64 + (m0 ^ P));        // nodes m0..+3
        float4 xb = *(const float4*)(xT + k * 64 + ((m0 + 4) ^ P));  // nodes m0+4..+7
        float4 w = *(const float4*)(W + k * D + nc);
        float xv0 = xa.x, xv1 = xa.y, xv2 = xa.z, xv3 = xa.w;
        float xv4 = xb.x, xv5 = xb.y, xv6 = xb.z, xv7 = xb.w;
        acc[0].x += xv0 * w.x; acc[0].y += xv0 * w.y; acc[0].z += xv0 * w.z; acc[0].w += xv0 * w.w;
        acc[1].x += xv1 * w.x; acc[1].y += xv1 * w.y; acc[1].z += xv1 * w.z; acc[1].w += xv1 * w.w;
        acc[2].x += xv2 * w.x; acc[2].y += xv2 * w.y; acc[2].z += xv2 * w.z; acc[2].w += xv2 * w.w;
        acc[3].x += xv3 * w.x; acc[3].y += xv3 * w.y; acc[3].z += xv3 * w.z; acc[3].w += xv3 * w.w;
        acc[4].x += xv4 * w.x; acc[4].y += xv4 * w.y; acc[4].z += xv4 * w.z; acc[4].w += xv4 * w.w;
        acc[5].x += xv5 * w.x; acc[5].y += xv5 * w.y; acc[5].z += xv5 * w.z; acc[5].w += xv5 * w.w;
        acc[6].x += xv6 * w.x; acc[6].y += xv6 * w.y; acc[6].z += xv6 * w.z; acc[6].w += xv6 * w.w;
        acc[7].x += xv7 * w.x; acc[7].y += xv7 * w.y; acc[7].z += xv7 * w.z; acc[7].w += xv7 * w.w;
    }
#pragma unroll
    for (int j = 0; j < 8; ++j) {
        int node = tileBase + m0 + j;
        if (node < NN) {
            float sc = scale ? scale[node] : 1.0f;
            h4v o;
            o[0] = (_Float16)(acc[j].x * sc);
            o[1] = (_Float16)(acc[j].y * sc);
            o[2] = (_Float16)(acc[j].z * sc);
            o[3] = (_Float16)(acc[j].w * sc);
            *(h4v*)(out + (size_t)node * D + nc) = o;
        }
    }
}

// ---------------- K1 (fused): blocks [0,KB) partition | [KB,KB+TFB) transform1 --------
// Partition: single-pass deterministic-slot slab sort (r5, proven).
// Transform1: tiled GEMM above; 4 tile-buffers, 8 tiles/block in 2 passes.
__global__ __launch_bounds__(PTB) void partition_tf1_kernel(
    const int* __restrict__ src, const int* __restrict__ dst,
    int* __restrict__ cntD, int* __restrict__ cntS,
    int* __restrict__ pbuf, unsigned char* __restrict__ qloc,
    const float* __restrict__ x, const float* __restrict__ W1,
    _Float16* __restrict__ t_h)
{
    __shared__ float xT[4][64 * 64];    // 64 KB
    int t = threadIdx.x, b = blockIdx.x;
    if (b >= KB) {
        int tb = b - KB;
        int pair = t >> 7;
#pragma unroll
        for (int pass = 0; pass < 2; ++pass) {
            if (pass) __syncthreads();
            int tile = (pass << 2) + pair;
            int tileBase = tb * 512 + (tile << 6);
            tile_transform(x, W1, (const float*)0, t_h, xT[pair], tileBase, t);
        }
        return;
    }
    // ---- partition: single pass, LDS cursors from deterministic bases ----
    __shared__ int hD[NBD], hS[NBS];
    for (int i = t; i < NBD; i += PTB) hD[i] = (i * KB + b) * CAPB;
    for (int i = t; i < NBS; i += PTB) hS[i] = (i * KB + b) * CAPS_PB;
    __syncthreads();
    const int4* s4 = (const int4*)src + (size_t)b * QPB;
    const int4* d4 = (const int4*)dst + (size_t)b * QPB;
    for (int i = t; i < QPB; i += PTB) {
        int4 a = s4[i], d = d4[i];
        int p;
        p = atomicAdd(&hD[d.x >> 9], 1); pbuf[p] = ((d.x & 511) << 17) | a.x;
        p = atomicAdd(&hD[d.y >> 9], 1); pbuf[p] = ((d.y & 511) << 17) | a.y;
        p = atomicAdd(&hD[d.z >> 9], 1); pbuf[p] = ((d.z & 511) << 17) | a.z;
        p = atomicAdd(&hD[d.w >> 9], 1); pbuf[p] = ((d.w & 511) << 17) | a.w;
        p = atomicAdd(&hS[a.x >> 8], 1); qloc[p] = (unsigned char)(a.x & 255);
        p = atomicAdd(&hS[a.y >> 8], 1); qloc[p] = (unsigned char)(a.y & 255);
        p = atomicAdd(&hS[a.z >> 8], 1); qloc[p] = (unsigned char)(a.z & 255);
        p = atomicAdd(&hS[a.w >> 8], 1); qloc[p] = (unsigned char)(a.w & 255);
    }
    __syncthreads();
    for (int i = t; i < NBD; i += PTB) cntD[i * KB + b] = hD[i] - (i * KB + b) * CAPB;
    for (int i = t; i < NBS; i += PTB) cntS[i * KB + b] = hS[i] - (i * KB + b) * CAPS_PB;
}

// ---------------- K2: scan — bucket totals + exclusive prefix -> rowbase ----------
__global__ __launch_bounds__(256) void scan_kernel(const int* __restrict__ cntD,
                                                   int* __restrict__ rowbase,
                                                   int* __restrict__ row_ptr) {
    __shared__ int tot[256];
    int t = threadIdx.x;
    int s = 0;
    if (t < NBD) {
        const int* p = cntD + t * KB;
        for (int b = 0; b < KB; ++b) s += p[b];
    }
    tot[t] = s;
    __syncthreads();
    if (t < 64) {
        int v[4];
        int sum = 0;
#pragma unroll
        for (int j = 0; j < 4; ++j) { v[j] = tot[t * 4 + j]; sum += v[j]; }
        int incl = sum;
        for (int o = 1; o < 64; o <<= 1) {
            int u = __shfl_up(incl, o, 64);
            if (t >= o) incl += u;
        }
        int run = incl - sum;
#pragma unroll
        for (int j = 0; j < 4; ++j) { rowbase[t * 4 + j] = run; run += v[j]; }
    }
    if (t == 255) row_ptr[NN] = NE;
}

// ---------------- K3: finalize (ragged per-cell runs; r5 structure) ----------------
__global__ __launch_bounds__(PTB) void finalize_kernel(
    const int* __restrict__ pbuf, const unsigned char* __restrict__ qloc,
    const int* __restrict__ cntD, const int* __restrict__ cntS,
    const int* __restrict__ rowbase,
    int* __restrict__ row_ptr, float* __restrict__ nsrc,
    float* __restrict__ ndst, int* __restrict__ esrc)
{
    int B = blockIdx.x, t = threadIdx.x;
    int lane = t & 63, w = t >> 6;
    if (B >= NBD) {
        int q = B - NBD;
        __shared__ int h[256];
        __shared__ int cs[KB];
        if (t < 256) h[t] = 0;
        if (t < KB) cs[t] = cntS[q * KB + t];
        __syncthreads();
        for (int r = w; r < KB; r += 8) {
            int c = cs[r];
            const unsigned char* run = qloc + ((size_t)q * KB + r) * CAPS_PB;
            for (int k = lane; k < c; k += 64) atomicAdd(&h[run[k]], 1);
        }
        __syncthreads();
        if (t < 256) {
            int n = (q << 8) + t;
            if (n < NN) nsrc[n] = 1.0f / sqrtf(fmaxf((float)h[t], 1.0f));
        }
        return;
    }
    __shared__ int fh[512], fcur[512];
    __shared__ int cl[KB];
    if (t < KB) cl[t] = cntD[B * KB + t];
    for (int i = t; i < 512; i += PTB) fh[i] = 0;
    __syncthreads();
    int beg = rowbase[B];
    for (int r = w; r < KB; r += 8) {
        int c = cl[r];
        const int* run = pbuf + ((size_t)B * KB + r) * CAPB;
        for (int k = lane; k < c; k += 64) atomicAdd(&fh[run[k] >> 17], 1);
    }
    __syncthreads();
    if (w == 0) {
        int v[8];
        int s = 0;
#pragma unroll
        for (int j = 0; j < 8; ++j) { v[j] = fh[lane * 8 + j]; s += v[j]; }
        int incl = s;
        for (int o = 1; o < 64; o <<= 1) {
            int u = __shfl_up(incl, o, 64);
            if (lane >= o) incl += u;
        }
        int run = incl - s;
#pragma unroll
        for (int j = 0; j < 8; ++j) {
            int bin = lane * 8 + j;
            fcur[bin] = run;
            int n = (B << 9) + bin;
            if (n < NN) {
                row_ptr[n] = beg + run;
                ndst[n] = 1.0f / sqrtf(fmaxf((float)v[j], 1.0f));
            }
            run += v[j];
        }
    }
    __syncthreads();
    for (int r = w; r < KB; r += 8) {
        int c = cl[r];
        const int* run = pbuf + ((size_t)B * KB + r) * CAPB;
        for (int k = lane; k < c; k += 64) {
            int v = run[k];
            int p = atomicAdd(&fcur[v >> 17], 1);
            esrc[beg + p] = v & 0x1FFFF;
        }
    }
}

// ---------------- transform layer 2: t[v] = fp16( nsrc[v] * (h1[v] @ W2) ) ----------
__global__ __launch_bounds__(PTB) void transform_kernel(const float* __restrict__ xin,
                                                        const float* __restrict__ W,
                                                        const float* __restrict__ nsrc,
                                                        _Float16* __restrict__ out) {
    __shared__ float xT[4][64 * 64];
    int t = threadIdx.x;
    int pair = t >> 7;
#pragma unroll
    for (int pass = 0; pass < 2; ++pass) {
        if (pass) __syncthreads();
        int tile = (pass << 2) + pair;
        int tileBase = blockIdx.x * 512 + (tile << 6);
        tile_transform(xin, W, nsrc, out, xT[pair], tileBase, t);
    }
}

// ---------------- aggregation (fp16 gather, fp32 accumulate; proven) ----------------
template<int RELU, int USE_NSRC>
__global__ __launch_bounds__(256) void aggregate_kernel(const _Float16* __restrict__ t,
                                                        const int* __restrict__ row_ptr,
                                                        const int* __restrict__ esrc,
                                                        const float* __restrict__ nsrc,
                                                        const float* __restrict__ ndst,
                                                        const float* __restrict__ bias,
                                                        float* __restrict__ out) {
    int node = (blockIdx.x * 256 + threadIdx.x) >> 6;
    int lane = threadIdx.x & 63;
    int g = lane >> 3, c = lane & 7;
    if (node >= NN) return;
    int beg = row_ptr[node], end = row_ptr[node + 1];
    float a0[8] = {0,0,0,0,0,0,0,0};
    float a1[8] = {0,0,0,0,0,0,0,0};
    int i = beg;
    for (; i + 16 <= end; i += 16) {
        int s0 = esrc[i + g];
        int s1 = esrc[i + 8 + g];
        float ns0 = USE_NSRC ? nsrc[s0] : 1.0f;
        float ns1 = USE_NSRC ? nsrc[s1] : 1.0f;
        h8v v0 = *(const h8v*)(t + (size_t)s0 * D + (c << 3));
        h8v v1 = *(const h8v*)(t + (size_t)s1 * D + (c << 3));
#pragma unroll
        for (int j = 0; j < 8; ++j) {
            if (USE_NSRC) { a0[j] += (float)v0[j] * ns0; a1[j] += (float)v1[j] * ns1; }
            else          { a0[j] += (float)v0[j];       a1[j] += (float)v1[j]; }
        }
    }
    for (; i < end; i += 8) {
        int e = i + g;
        if (e < end) {
            int s = esrc[e];
            float ns = USE_NSRC ? nsrc[s] : 1.0f;
            h8v v = *(const h8v*)(t + (size_t)s * D + (c << 3));
#pragma unroll
            for (int j = 0; j < 8; ++j) {
                if (USE_NSRC) a0[j] += (float)v[j] * ns;
                else          a0[j] += (float)v[j];
            }
        }
    }
#pragma unroll
    for (int j = 0; j < 8; ++j) a0[j] += a1[j];
#pragma unroll
    for (int j = 0; j < 8; ++j) {
        a0[j] += __shfl_xor(a0[j], 8, 64);
        a0[j] += __shfl_xor(a0[j], 16, 64);
        a0[j] += __shfl_xor(a0[j], 32, 64);
    }
    float nd = ndst[node];
    float4 blo = *(const float4*)(bias + (c << 3));
    float4 bhi = *(const float4*)(bias + (c << 3) + 4);
    float h[8];
    h[0] = a0[0] * nd + blo.x; h[1] = a0[1] * nd + blo.y;
    h[2] = a0[2] * nd + blo.z; h[3] = a0[3] * nd + blo.w;
    h[4] = a0[4] * nd + bhi.x; h[5] = a0[5] * nd + bhi.y;
    h[6] = a0[6] * nd + bhi.z; h[7] = a0[7] * nd + bhi.w;
    if (RELU) {
#pragma unroll
        for (int j = 0; j < 8; ++j) h[j] = fmaxf(h[j], 0.f);
    }
    if (g == 0) {
        float4 o0 = {h[0], h[1], h[2], h[3]};
        float4 o1 = {h[4], h[5], h[6], h[7]};
        *(float4*)(out + (size_t)node * D + (c << 3)) = o0;
        *(float4*)(out + (size_t)node * D + (c << 3) + 4) = o1;
    }
}

// ---------------- launcher ----------------
extern "C" void kernel_launch(void* const* d_in, const int* in_sizes, int n_in,
                              void* d_out, int out_size, void* d_ws, size_t ws_size,
                              hipStream_t stream) {
    const float* x  = (const float*)d_in[0];
    const int* src  = (const int*)d_in[1];
    const int* dst  = (const int*)d_in[2];
    const float* W1 = (const float*)d_in[3];
    const float* b1 = (const float*)d_in[4];
    const float* W2 = (const float*)d_in[5];
    const float* b2 = (const float*)d_in[6];
    float* out = (float*)d_out;

    size_t off = 0;
    auto alloc = [&](size_t bytes) -> void* {
        void* p = (char*)d_ws + off;
        off += (bytes + 255) & ~(size_t)255;
        return p;
    };
    int* row_ptr  = (int*)alloc((size_t)(NN + 1) * 4);
    float* nsrc   = (float*)alloc((size_t)NN * 4);
    float* ndst   = (float*)alloc((size_t)NN * 4);
    int* rowbase  = (int*)alloc((size_t)256 * 4);
    int* cntD     = (int*)alloc((size_t)NBD * KB * 4);           // 98 KB
    int* cntS     = (int*)alloc((size_t)NBS * KB * 4);           // 196 KB
    int* esrc     = (int*)alloc((size_t)NE * 4);                 // 6.4 MB
    _Float16* t_h = (_Float16*)alloc((size_t)NN * D * 2);        // 12.8 MB
    float* h1     = (float*)alloc((size_t)NN * D * 4);           // 25.6 MB
    (void)ws_size;

    // prep scratch aliases h1 (dead until aggregate1 writes it):
    // pbuf 196*125*128*4 = 12.54MB | qloc 391*125*80 = 3.91MB -> 16.5MB < 25.6MB
    int* pbuf = (int*)h1;
    unsigned char* qloc = (unsigned char*)(pbuf + (size_t)NBD * KB * CAPB);

    partition_tf1_kernel<<<KB + TFB, PTB, 0, stream>>>(src, dst, cntD, cntS,
                                                       pbuf, qloc, x, W1, t_h);
    scan_kernel<<<1, 256, 0, stream>>>(cntD, rowbase, row_ptr);
    finalize_kernel<<<NBD + NBS, PTB, 0, stream>>>(pbuf, qloc, cntD, cntS, rowbase,
                                                   row_ptr, nsrc, ndst, esrc);

    int ag_blocks = NN / 4;
    aggregate_kernel<1, 1><<<ag_blocks, 256, 0, stream>>>(t_h, row_ptr, esrc, nsrc, ndst, b1, h1);
    transform_kernel<<<TFB, PTB, 0, stream>>>(h1, W2, nsrc, t_h);
    aggregate_kernel<0, 0><<<ag_blocks, 256, 0, stream>>>(t_h, row_ptr, esrc, nsrc, ndst, b2, out);
}

// Round 7
// 251.029 us; speedup vs baseline: 1.1593x; 1.1593x over previous
//
#include <hip/hip_runtime.h>
#include <math.h>

#define NN 100000
#define NE 1600000
#define D 64
#define NQ (NE / 4)

#define NBD 196                     // dst buckets, width 512 (dst>>9)
#define CAPD 10240                  // slab capacity (mean 8192, sd 90: +22 sigma)
#define NBS 391                     // src buckets, width 256 (src>>8)
#define CAPS 5120                   // slab capacity (mean 4096, sd 64: +16 sigma)

#define KB 250                      // partition blocks (proven; KB=1000 regressed r2)
#define QPB (NQ / KB)               // 1600 int4 quads per block (exact)
#define PTB 512
#define TFB 782                     // transform blocks: 128 nodes each (782*128=100096)

typedef _Float16 h4v __attribute__((ext_vector_type(4)));
typedef _Float16 h8v __attribute__((ext_vector_type(8)));

// ============ tiled transform core: 64-node tile, 4 waves, out = fp16(scale*(x@W)) ====
// Per wave per k: 1 ds_read_b128 (xT swizzled, <=2-way) + 1 broadcast dwordx4 (W, L1)
// + 16 FMA. 4 LDS-ops/node vs 32 for the old shuffle matmul (the ~50us K1 LDS floor).
// xT[k][m ^ (k&60)]: staging writes and compute reads both conflict-benign; XOR by a
// multiple of 4 keeps float4 blocks intact. fp32 math, k ascending (precision as before).
__device__ __forceinline__ void tile_tf(
    const float* __restrict__ in, const float* __restrict__ W,
    const float* __restrict__ scale, _Float16* __restrict__ out,
    float* xT, int tileBase, int lt /*0..255*/)
{
    // ---- stage: 256 threads, 64 nodes x 64 k ----
    {
        int c4 = (lt & 15) << 2;        // k-base, multiple of 4
        int r0 = lt >> 4;               // 0..15
#pragma unroll
        for (int p = 0; p < 4; ++p) {
            int r = r0 + (p << 4);      // node-in-tile 0..63
            int node = tileBase + r;
            int nl = node < NN ? node : NN - 1;
            float4 v = *(const float4*)(in + (size_t)nl * D + c4);
            xT[(c4 + 0) * 64 + (r ^ c4)] = v.x;
            xT[(c4 + 1) * 64 + (r ^ c4)] = v.y;
            xT[(c4 + 2) * 64 + (r ^ c4)] = v.z;
            xT[(c4 + 3) * 64 + (r ^ c4)] = v.w;
        }
    }
    __syncthreads();
    // ---- compute: wave w (0..3) covers cols w*16+(lane&3)*4; lane owns 4 nodes ----
    int lane = lt & 63;
    int w = lt >> 6;                    // 0..3
    int m0 = (lane >> 2) << 2;          // node quad base
    int nc = (w << 4) + ((lane & 3) << 2);
    float4 a0 = {0,0,0,0}, a1 = {0,0,0,0}, a2 = {0,0,0,0}, a3 = {0,0,0,0};
#pragma unroll 8
    for (int k = 0; k < 64; ++k) {
        int P = k & 60;
        float4 xa = *(const float4*)(xT + k * 64 + (m0 ^ P));   // nodes m0..m0+3
        float4 wv = *(const float4*)(W + k * D + nc);
        a0.x += xa.x * wv.x; a0.y += xa.x * wv.y; a0.z += xa.x * wv.z; a0.w += xa.x * wv.w;
        a1.x += xa.y * wv.x; a1.y += xa.y * wv.y; a1.z += xa.y * wv.z; a1.w += xa.y * wv.w;
        a2.x += xa.z * wv.x; a2.y += xa.z * wv.y; a2.z += xa.z * wv.z; a2.w += xa.z * wv.w;
        a3.x += xa.w * wv.x; a3.y += xa.w * wv.y; a3.z += xa.w * wv.z; a3.w += xa.w * wv.w;
    }
    float4 acc[4] = {a0, a1, a2, a3};
#pragma unroll
    for (int j = 0; j < 4; ++j) {
        int node = tileBase + m0 + j;
        if (node < NN) {
            float sc = scale ? scale[node] : 1.0f;
            h4v o;
            o[0] = (_Float16)(acc[j].x * sc); o[1] = (_Float16)(acc[j].y * sc);
            o[2] = (_Float16)(acc[j].z * sc); o[3] = (_Float16)(acc[j].w * sc);
            *(h4v*)(out + (size_t)node * D + nc) = o;
        }
    }
}

// ---------------- K1 (fused): blocks [0,KB) partition | [KB,KB+TFB) transform1 --------
// Partition: r4-proven 2-pass slab sort with bulk reservation.
// LDS is a 32KB union: transform uses 2x 64-node xT tiles; partition aliases 2.3KB
// histograms into it -> LDS_Block_Size ~33KB -> 4 blocks/CU (r6's 68KB gave 2).
__global__ __launch_bounds__(PTB) void partition_tf1_kernel(
    const int* __restrict__ src, const int* __restrict__ dst,
    int* __restrict__ gcurD, int* __restrict__ gcurS,
    int* __restrict__ pbuf, unsigned char* __restrict__ qloc,
    const float* __restrict__ x, const float* __restrict__ W1,
    _Float16* __restrict__ t_h)
{
    __shared__ float smem[2 * 64 * 64];     // 32 KB union
    int t = threadIdx.x, b = blockIdx.x;
    if (b >= KB) {
        // ---- transform1: two 64-node tiles, 4 waves each (t_h = fp16(x@W1), no nsrc)
        int half = t >> 8;                  // 0/1: tile select
        int lt = t & 255;
        tile_tf(x, W1, (const float*)0, t_h,
                smem + half * (64 * 64), (b - KB) * 128 + half * 64, lt);
        return;
    }
    // ---- partition (r4-proven) ----
    int* hD = (int*)smem;
    int* hS = hD + NBD;
    for (int i = t; i < NBD; i += PTB) hD[i] = 0;
    for (int i = t; i < NBS; i += PTB) hS[i] = 0;
    __syncthreads();
    const int4* s4 = (const int4*)src + (size_t)b * QPB;
    const int4* d4 = (const int4*)dst + (size_t)b * QPB;
    for (int i = t; i < QPB; i += PTB) {
        int4 a = s4[i], d = d4[i];
        atomicAdd(&hD[d.x >> 9], 1); atomicAdd(&hD[d.y >> 9], 1);
        atomicAdd(&hD[d.z >> 9], 1); atomicAdd(&hD[d.w >> 9], 1);
        atomicAdd(&hS[a.x >> 8], 1); atomicAdd(&hS[a.y >> 8], 1);
        atomicAdd(&hS[a.z >> 8], 1); atomicAdd(&hS[a.w >> 8], 1);
    }
    __syncthreads();
    for (int i = t; i < NBD; i += PTB) {
        int c = hD[i];
        int base = c ? atomicAdd(&gcurD[i], c) : 0;
        hD[i] = i * CAPD + base;            // becomes write cursor
    }
    for (int i = t; i < NBS; i += PTB) {
        int c = hS[i];
        int base = c ? atomicAdd(&gcurS[i], c) : 0;
        hS[i] = i * CAPS + base;
    }
    __syncthreads();
    for (int i = t; i < QPB; i += PTB) {
        int4 a = s4[i], d = d4[i];
        int p;
        p = atomicAdd(&hD[d.x >> 9], 1); pbuf[p] = ((d.x & 511) << 17) | a.x;
        p = atomicAdd(&hD[d.y >> 9], 1); pbuf[p] = ((d.y & 511) << 17) | a.y;
        p = atomicAdd(&hD[d.z >> 9], 1); pbuf[p] = ((d.z & 511) << 17) | a.z;
        p = atomicAdd(&hD[d.w >> 9], 1); pbuf[p] = ((d.w & 511) << 17) | a.w;
        p = atomicAdd(&hS[a.x >> 8], 1); qloc[p] = (unsigned char)(a.x & 255);
        p = atomicAdd(&hS[a.y >> 8], 1); qloc[p] = (unsigned char)(a.y & 255);
        p = atomicAdd(&hS[a.z >> 8], 1); qloc[p] = (unsigned char)(a.z & 255);
        p = atomicAdd(&hS[a.w >> 8], 1); qloc[p] = (unsigned char)(a.w & 255);
    }
}

// ---------------- K2: finalize (r4-proven) ----------------
__global__ __launch_bounds__(PTB) void finalize_kernel(
    const int* __restrict__ pbuf, const unsigned char* __restrict__ qloc,
    const int* __restrict__ gcurD, const int* __restrict__ gcurS,
    int* __restrict__ row_ptr, float* __restrict__ nsrc,
    float* __restrict__ ndst, int* __restrict__ esrc)
{
    int B = blockIdx.x, t = threadIdx.x;
    int lane = t & 63, w = t >> 6;
    if (B >= NBD) {
        __shared__ int h[256];
        int q = B - NBD;
        int cnt = gcurS[q];
        const unsigned char* slab = qloc + (size_t)q * CAPS;
        if (t < 256) h[t] = 0;
        __syncthreads();
        for (int i = t; i < cnt; i += PTB) atomicAdd(&h[slab[i]], 1);
        __syncthreads();
        if (t < 256) {
            int n = (q << 8) + t;
            if (n < NN) nsrc[n] = 1.0f / sqrtf(fmaxf((float)h[t], 1.0f));
        }
        return;
    }
    __shared__ int fh[512], fcur[512];
    __shared__ int sbeg;
    int cnt = gcurD[B];
    const int* slab = pbuf + (size_t)B * CAPD;
    for (int i = t; i < 512; i += PTB) fh[i] = 0;
    if (w == 0) {
        int s = 0;
        for (int j = lane; j < B; j += 64) s += gcurD[j];
        for (int o = 32; o > 0; o >>= 1) s += __shfl_xor(s, o, 64);
        if (lane == 0) sbeg = s;
    }
    if (B == 0 && t == 128) row_ptr[NN] = NE;
    __syncthreads();
    int beg = sbeg;
    for (int i = t; i < cnt; i += PTB) atomicAdd(&fh[slab[i] >> 17], 1);
    __syncthreads();
    if (w == 0) {
        int v[8];
        int s = 0;
#pragma unroll
        for (int j = 0; j < 8; ++j) { v[j] = fh[lane * 8 + j]; s += v[j]; }
        int incl = s;
        for (int o = 1; o < 64; o <<= 1) {
            int u = __shfl_up(incl, o, 64);
            if (lane >= o) incl += u;
        }
        int run = incl - s;
#pragma unroll
        for (int j = 0; j < 8; ++j) {
            int bin = lane * 8 + j;
            fcur[bin] = run;
            int n = (B << 9) + bin;
            if (n < NN) {
                row_ptr[n] = beg + run;
                ndst[n] = 1.0f / sqrtf(fmaxf((float)v[j], 1.0f));
            }
            run += v[j];
        }
    }
    __syncthreads();
    for (int i = t; i < cnt; i += PTB) {
        int v = slab[i];
        int p = atomicAdd(&fcur[v >> 17], 1);
        esrc[beg + p] = v & 0x1FFFF;
    }
}

// ---------------- transform layer 2: t[v] = fp16( nsrc[v] * (h1[v] @ W2) ) ----------
__global__ __launch_bounds__(PTB) void transform_kernel(const float* __restrict__ xin,
                                                        const float* __restrict__ W,
                                                        const float* __restrict__ nsrc,
                                                        _Float16* __restrict__ out) {
    __shared__ float smem[2 * 64 * 64];
    int t = threadIdx.x;
    int half = t >> 8;
    int lt = t & 255;
    tile_tf(xin, W, nsrc, out, smem + half * (64 * 64),
            blockIdx.x * 128 + half * 64, lt);
}

// ---------------- aggregation (fp16 gather, fp32 accumulate; proven) ----------------
template<int RELU, int USE_NSRC>
__global__ __launch_bounds__(256) void aggregate_kernel(const _Float16* __restrict__ t,
                                                        const int* __restrict__ row_ptr,
                                                        const int* __restrict__ esrc,
                                                        const float* __restrict__ nsrc,
                                                        const float* __restrict__ ndst,
                                                        const float* __restrict__ bias,
                                                        float* __restrict__ out) {
    int node = (blockIdx.x * 256 + threadIdx.x) >> 6;
    int lane = threadIdx.x & 63;
    int g = lane >> 3, c = lane & 7;
    if (node >= NN) return;
    int beg = row_ptr[node], end = row_ptr[node + 1];
    float a0[8] = {0,0,0,0,0,0,0,0};
    float a1[8] = {0,0,0,0,0,0,0,0};
    int i = beg;
    for (; i + 16 <= end; i += 16) {
        int s0 = esrc[i + g];
        int s1 = esrc[i + 8 + g];
        float ns0 = USE_NSRC ? nsrc[s0] : 1.0f;
        float ns1 = USE_NSRC ? nsrc[s1] : 1.0f;
        h8v v0 = *(const h8v*)(t + (size_t)s0 * D + (c << 3));
        h8v v1 = *(const h8v*)(t + (size_t)s1 * D + (c << 3));
#pragma unroll
        for (int j = 0; j < 8; ++j) {
            if (USE_NSRC) { a0[j] += (float)v0[j] * ns0; a1[j] += (float)v1[j] * ns1; }
            else          { a0[j] += (float)v0[j];       a1[j] += (float)v1[j]; }
        }
    }
    for (; i < end; i += 8) {
        int e = i + g;
        if (e < end) {
            int s = esrc[e];
            float ns = USE_NSRC ? nsrc[s] : 1.0f;
            h8v v = *(const h8v*)(t + (size_t)s * D + (c << 3));
#pragma unroll
            for (int j = 0; j < 8; ++j) {
                if (USE_NSRC) a0[j] += (float)v[j] * ns;
                else          a0[j] += (float)v[j];
            }
        }
    }
#pragma unroll
    for (int j = 0; j < 8; ++j) a0[j] += a1[j];
#pragma unroll
    for (int j = 0; j < 8; ++j) {
        a0[j] += __shfl_xor(a0[j], 8, 64);
        a0[j] += __shfl_xor(a0[j], 16, 64);
        a0[j] += __shfl_xor(a0[j], 32, 64);
    }
    float nd = ndst[node];
    float4 blo = *(const float4*)(bias + (c << 3));
    float4 bhi = *(const float4*)(bias + (c << 3) + 4);
    float h[8];
    h[0] = a0[0] * nd + blo.x; h[1] = a0[1] * nd + blo.y;
    h[2] = a0[2] * nd + blo.z; h[3] = a0[3] * nd + blo.w;
    h[4] = a0[4] * nd + bhi.x; h[5] = a0[5] * nd + bhi.y;
    h[6] = a0[6] * nd + bhi.z; h[7] = a0[7] * nd + bhi.w;
    if (RELU) {
#pragma unroll
        for (int j = 0; j < 8; ++j) h[j] = fmaxf(h[j], 0.f);
    }
    if (g == 0) {
        float4 o0 = {h[0], h[1], h[2], h[3]};
        float4 o1 = {h[4], h[5], h[6], h[7]};
        *(float4*)(out + (size_t)node * D + (c << 3)) = o0;
        *(float4*)(out + (size_t)node * D + (c << 3) + 4) = o1;
    }
}

// ---------------- launcher ----------------
extern "C" void kernel_launch(void* const* d_in, const int* in_sizes, int n_in,
                              void* d_out, int out_size, void* d_ws, size_t ws_size,
                              hipStream_t stream) {
    const float* x  = (const float*)d_in[0];
    const int* src  = (const int*)d_in[1];
    const int* dst  = (const int*)d_in[2];
    const float* W1 = (const float*)d_in[3];
    const float* b1 = (const float*)d_in[4];
    const float* W2 = (const float*)d_in[5];
    const float* b2 = (const float*)d_in[6];
    float* out = (float*)d_out;

    size_t off = 0;
    auto alloc = [&](size_t bytes) -> void* {
        void* p = (char*)d_ws + off;
        off += (bytes + 255) & ~(size_t)255;
        return p;
    };
    int* row_ptr  = (int*)alloc((size_t)(NN + 1) * 4);
    float* nsrc   = (float*)alloc((size_t)NN * 4);
    float* ndst   = (float*)alloc((size_t)NN * 4);
    int* gcurD    = (int*)alloc((size_t)(NBD + NBS) * 4);
    int* esrc     = (int*)alloc((size_t)NE * 4);                 // 6.4 MB
    _Float16* t_h = (_Float16*)alloc((size_t)NN * D * 2);        // 12.8 MB
    float* h1     = (float*)alloc((size_t)NN * D * 4);           // 25.6 MB
    (void)ws_size;
    int* gcurS = gcurD + NBD;

    // prep scratch aliases h1 (dead until aggregate1 writes it):
    // pbuf 196*10240*4 = 8.0MB | qloc 391*5120 = 2.0MB  -> 10MB < 25.6MB
    int* pbuf = (int*)h1;
    unsigned char* qloc = (unsigned char*)(pbuf + (size_t)NBD * CAPD);

    hipMemsetAsync(gcurD, 0, (size_t)(NBD + NBS) * 4, stream);

    partition_tf1_kernel<<<KB + TFB, PTB, 0, stream>>>(src, dst, gcurD, gcurS,
                                                       pbuf, qloc, x, W1, t_h);
    finalize_kernel<<<NBD + NBS, PTB, 0, stream>>>(pbuf, qloc, gcurD, gcurS,
                                                   row_ptr, nsrc, ndst, esrc);

    int ag_blocks = NN / 4;
    aggregate_kernel<1, 1><<<ag_blocks, 256, 0, stream>>>(t_h, row_ptr, esrc, nsrc, ndst, b1, h1);
    transform_kernel<<<TFB, PTB, 0, stream>>>(h1, W2, nsrc, t_h);
    aggregate_kernel<0, 0><<<ag_blocks, 256, 0, stream>>>(t_h, row_ptr, esrc, nsrc, ndst, b2, out);
}

// Round 8
// 236.941 us; speedup vs baseline: 1.2282x; 1.0595x over previous
//
#include <hip/hip_runtime.h>
#include <math.h>

#define NN 100000
#define NE 1600000
#define D 64
#define NQ (NE / 4)

#define NBD 196                     // dst buckets, width 512 (dst>>9)
#define CAPD 10240                  // slab capacity (mean 8192, sd 90: +22 sigma)
#define NBS 391                     // src buckets, width 256 (src>>8)
#define CAPS 5120                   // slab capacity (mean 4096, sd 64: +16 sigma)

#define KB 250                      // partition blocks (proven; KB=1000 regressed r2)
#define QPB (NQ / KB)               // 1600 int4 quads per block (exact)
#define PTB 512
#define TFB 782                     // transform blocks: 128 nodes each (782*128=100096)

typedef _Float16 h4v __attribute__((ext_vector_type(4)));
typedef _Float16 h8v __attribute__((ext_vector_type(8)));

// ============ tiled transform core: 64-node tile, 4 waves, out = fp16(scale*(x@W)) ====
// (r7-proven) Per wave per k: 1 ds_read_b128 (xT swizzled) + 1 broadcast dwordx4 (W)
// + 16 FMA. fp32 math, k ascending.
__device__ __forceinline__ void tile_tf(
    const float* __restrict__ in, const float* __restrict__ W,
    const float* __restrict__ scale, _Float16* __restrict__ out,
    float* xT, int tileBase, int lt /*0..255*/)
{
    {
        int c4 = (lt & 15) << 2;        // k-base, multiple of 4
        int r0 = lt >> 4;               // 0..15
#pragma unroll
        for (int p = 0; p < 4; ++p) {
            int r = r0 + (p << 4);      // node-in-tile 0..63
            int node = tileBase + r;
            int nl = node < NN ? node : NN - 1;
            float4 v = *(const float4*)(in + (size_t)nl * D + c4);
            xT[(c4 + 0) * 64 + (r ^ c4)] = v.x;
            xT[(c4 + 1) * 64 + (r ^ c4)] = v.y;
            xT[(c4 + 2) * 64 + (r ^ c4)] = v.z;
            xT[(c4 + 3) * 64 + (r ^ c4)] = v.w;
        }
    }
    __syncthreads();
    int lane = lt & 63;
    int w = lt >> 6;                    // 0..3
    int m0 = (lane >> 2) << 2;          // node quad base
    int nc = (w << 4) + ((lane & 3) << 2);
    float4 a0 = {0,0,0,0}, a1 = {0,0,0,0}, a2 = {0,0,0,0}, a3 = {0,0,0,0};
#pragma unroll 8
    for (int k = 0; k < 64; ++k) {
        int P = k & 60;
        float4 xa = *(const float4*)(xT + k * 64 + (m0 ^ P));   // nodes m0..m0+3
        float4 wv = *(const float4*)(W + k * D + nc);
        a0.x += xa.x * wv.x; a0.y += xa.x * wv.y; a0.z += xa.x * wv.z; a0.w += xa.x * wv.w;
        a1.x += xa.y * wv.x; a1.y += xa.y * wv.y; a1.z += xa.y * wv.z; a1.w += xa.y * wv.w;
        a2.x += xa.z * wv.x; a2.y += xa.z * wv.y; a2.z += xa.z * wv.z; a2.w += xa.z * wv.w;
        a3.x += xa.w * wv.x; a3.y += xa.w * wv.y; a3.z += xa.w * wv.z; a3.w += xa.w * wv.w;
    }
    float4 acc[4] = {a0, a1, a2, a3};
#pragma unroll
    for (int j = 0; j < 4; ++j) {
        int node = tileBase + m0 + j;
        if (node < NN) {
            float sc = scale ? scale[node] : 1.0f;
            h4v o;
            o[0] = (_Float16)(acc[j].x * sc); o[1] = (_Float16)(acc[j].y * sc);
            o[2] = (_Float16)(acc[j].z * sc); o[3] = (_Float16)(acc[j].w * sc);
            *(h4v*)(out + (size_t)node * D + nc) = o;
        }
    }
}

// ---------------- K1 (fused): blocks [0,KB) partition | [KB,KB+TFB) transform1 --------
__global__ __launch_bounds__(PTB) void partition_tf1_kernel(
    const int* __restrict__ src, const int* __restrict__ dst,
    int* __restrict__ gcurD, int* __restrict__ gcurS,
    int* __restrict__ pbuf, unsigned char* __restrict__ qloc,
    const float* __restrict__ x, const float* __restrict__ W1,
    _Float16* __restrict__ t_h)
{
    __shared__ float smem[2 * 64 * 64];     // 32 KB union
    int t = threadIdx.x, b = blockIdx.x;
    if (b >= KB) {
        int half = t >> 8;                  // 0/1: tile select
        int lt = t & 255;
        tile_tf(x, W1, (const float*)0, t_h,
                smem + half * (64 * 64), (b - KB) * 128 + half * 64, lt);
        return;
    }
    // ---- partition (r4-proven) ----
    int* hD = (int*)smem;
    int* hS = hD + NBD;
    for (int i = t; i < NBD; i += PTB) hD[i] = 0;
    for (int i = t; i < NBS; i += PTB) hS[i] = 0;
    __syncthreads();
    const int4* s4 = (const int4*)src + (size_t)b * QPB;
    const int4* d4 = (const int4*)dst + (size_t)b * QPB;
    for (int i = t; i < QPB; i += PTB) {
        int4 a = s4[i], d = d4[i];
        atomicAdd(&hD[d.x >> 9], 1); atomicAdd(&hD[d.y >> 9], 1);
        atomicAdd(&hD[d.z >> 9], 1); atomicAdd(&hD[d.w >> 9], 1);
        atomicAdd(&hS[a.x >> 8], 1); atomicAdd(&hS[a.y >> 8], 1);
        atomicAdd(&hS[a.z >> 8], 1); atomicAdd(&hS[a.w >> 8], 1);
    }
    __syncthreads();
    for (int i = t; i < NBD; i += PTB) {
        int c = hD[i];
        int base = c ? atomicAdd(&gcurD[i], c) : 0;
        hD[i] = i * CAPD + base;            // becomes write cursor
    }
    for (int i = t; i < NBS; i += PTB) {
        int c = hS[i];
        int base = c ? atomicAdd(&gcurS[i], c) : 0;
        hS[i] = i * CAPS + base;
    }
    __syncthreads();
    for (int i = t; i < QPB; i += PTB) {
        int4 a = s4[i], d = d4[i];
        int p;
        p = atomicAdd(&hD[d.x >> 9], 1); pbuf[p] = ((d.x & 511) << 17) | a.x;
        p = atomicAdd(&hD[d.y >> 9], 1); pbuf[p] = ((d.y & 511) << 17) | a.y;
        p = atomicAdd(&hD[d.z >> 9], 1); pbuf[p] = ((d.z & 511) << 17) | a.z;
        p = atomicAdd(&hD[d.w >> 9], 1); pbuf[p] = ((d.w & 511) << 17) | a.w;
        p = atomicAdd(&hS[a.x >> 8], 1); qloc[p] = (unsigned char)(a.x & 255);
        p = atomicAdd(&hS[a.y >> 8], 1); qloc[p] = (unsigned char)(a.y & 255);
        p = atomicAdd(&hS[a.z >> 8], 1); qloc[p] = (unsigned char)(a.z & 255);
        p = atomicAdd(&hS[a.w >> 8], 1); qloc[p] = (unsigned char)(a.w & 255);
    }
}

// ---------------- K2: finalize (r4-proven) ----------------
__global__ __launch_bounds__(PTB) void finalize_kernel(
    const int* __restrict__ pbuf, const unsigned char* __restrict__ qloc,
    const int* __restrict__ gcurD, const int* __restrict__ gcurS,
    int* __restrict__ row_ptr, float* __restrict__ nsrc,
    float* __restrict__ ndst, int* __restrict__ esrc)
{
    int B = blockIdx.x, t = threadIdx.x;
    int lane = t & 63, w = t >> 6;
    if (B >= NBD) {
        __shared__ int h[256];
        int q = B - NBD;
        int cnt = gcurS[q];
        const unsigned char* slab = qloc + (size_t)q * CAPS;
        if (t < 256) h[t] = 0;
        __syncthreads();
        for (int i = t; i < cnt; i += PTB) atomicAdd(&h[slab[i]], 1);
        __syncthreads();
        if (t < 256) {
            int n = (q << 8) + t;
            if (n < NN) nsrc[n] = 1.0f / sqrtf(fmaxf((float)h[t], 1.0f));
        }
        return;
    }
    __shared__ int fh[512], fcur[512];
    __shared__ int sbeg;
    int cnt = gcurD[B];
    const int* slab = pbuf + (size_t)B * CAPD;
    for (int i = t; i < 512; i += PTB) fh[i] = 0;
    if (w == 0) {
        int s = 0;
        for (int j = lane; j < B; j += 64) s += gcurD[j];
        for (int o = 32; o > 0; o >>= 1) s += __shfl_xor(s, o, 64);
        if (lane == 0) sbeg = s;
    }
    if (B == 0 && t == 128) row_ptr[NN] = NE;
    __syncthreads();
    int beg = sbeg;
    for (int i = t; i < cnt; i += PTB) atomicAdd(&fh[slab[i] >> 17], 1);
    __syncthreads();
    if (w == 0) {
        int v[8];
        int s = 0;
#pragma unroll
        for (int j = 0; j < 8; ++j) { v[j] = fh[lane * 8 + j]; s += v[j]; }
        int incl = s;
        for (int o = 1; o < 64; o <<= 1) {
            int u = __shfl_up(incl, o, 64);
            if (lane >= o) incl += u;
        }
        int run = incl - s;
#pragma unroll
        for (int j = 0; j < 8; ++j) {
            int bin = lane * 8 + j;
            fcur[bin] = run;
            int n = (B << 9) + bin;
            if (n < NN) {
                row_ptr[n] = beg + run;
                ndst[n] = 1.0f / sqrtf(fmaxf((float)v[j], 1.0f));
            }
            run += v[j];
        }
    }
    __syncthreads();
    for (int i = t; i < cnt; i += PTB) {
        int v = slab[i];
        int p = atomicAdd(&fcur[v >> 17], 1);
        esrc[beg + p] = v & 0x1FFFF;
    }
}

// ---------------- transform layer 2: t[v] = fp16( nsrc[v] * (h1[v] @ W2) ) ----------
__global__ __launch_bounds__(PTB) void transform_kernel(const float* __restrict__ xin,
                                                        const float* __restrict__ W,
                                                        const float* __restrict__ nsrc,
                                                        _Float16* __restrict__ out) {
    __shared__ float smem[2 * 64 * 64];
    int t = threadIdx.x;
    int half = t >> 8;
    int lt = t & 255;
    tile_tf(xin, W, nsrc, out, smem + half * (64 * 64),
            blockIdx.x * 128 + half * 64, lt);
}

// ---------------- aggregation: 2 nodes/wave, 4 edge-slots x 8 ch each ----------------
// r7 counters: 47.6us, VALU 50%, HBM 30%, L2-traffic 4.3 of 34.5 TB/s -> latency-bound
// on the row_ptr->esrc->gather chain with only 2 independent streams/wave.
// 2 nodes per wave (half = lane>>5) + 2 unrolled streams = 4 chains/wave at VGPR~28:
// 128 outstanding gathers/CU (2x r7). Reduce is xor 8,16 within the 32-lane half.
template<int RELU, int USE_NSRC>
__global__ __launch_bounds__(256) void aggregate_kernel(const _Float16* __restrict__ t,
                                                        const int* __restrict__ row_ptr,
                                                        const int* __restrict__ esrc,
                                                        const float* __restrict__ nsrc,
                                                        const float* __restrict__ ndst,
                                                        const float* __restrict__ bias,
                                                        float* __restrict__ out) {
    int wid = (blockIdx.x * 256 + threadIdx.x) >> 6;
    int lane = threadIdx.x & 63;
    int half = lane >> 5;
    int l5 = lane & 31;
    int g = l5 >> 3, c = l5 & 7;        // 4 edge slots x 8 channel-groups
    int node = wid * 2 + half;
    if (node >= NN) return;
    int beg = row_ptr[node], end = row_ptr[node + 1];
    float a0[8] = {0,0,0,0,0,0,0,0};
    float a1[8] = {0,0,0,0,0,0,0,0};
    int i = beg;
    for (; i + 8 <= end; i += 8) {
        int s0 = esrc[i + g];
        int s1 = esrc[i + 4 + g];
        float ns0 = USE_NSRC ? nsrc[s0] : 1.0f;
        float ns1 = USE_NSRC ? nsrc[s1] : 1.0f;
        h8v v0 = *(const h8v*)(t + (size_t)s0 * D + (c << 3));
        h8v v1 = *(const h8v*)(t + (size_t)s1 * D + (c << 3));
#pragma unroll
        for (int j = 0; j < 8; ++j) {
            if (USE_NSRC) { a0[j] += (float)v0[j] * ns0; a1[j] += (float)v1[j] * ns1; }
            else          { a0[j] += (float)v0[j];       a1[j] += (float)v1[j]; }
        }
    }
    for (; i < end; i += 4) {
        int e = i + g;
        if (e < end) {
            int s = esrc[e];
            float ns = USE_NSRC ? nsrc[s] : 1.0f;
            h8v v = *(const h8v*)(t + (size_t)s * D + (c << 3));
#pragma unroll
            for (int j = 0; j < 8; ++j) {
                if (USE_NSRC) a0[j] += (float)v[j] * ns;
                else          a0[j] += (float)v[j];
            }
        }
    }
#pragma unroll
    for (int j = 0; j < 8; ++j) a0[j] += a1[j];
#pragma unroll
    for (int j = 0; j < 8; ++j) {
        a0[j] += __shfl_xor(a0[j], 8, 64);
        a0[j] += __shfl_xor(a0[j], 16, 64);
    }
    float nd = ndst[node];
    float4 blo = *(const float4*)(bias + (c << 3));
    float4 bhi = *(const float4*)(bias + (c << 3) + 4);
    float h[8];
    h[0] = a0[0] * nd + blo.x; h[1] = a0[1] * nd + blo.y;
    h[2] = a0[2] * nd + blo.z; h[3] = a0[3] * nd + blo.w;
    h[4] = a0[4] * nd + bhi.x; h[5] = a0[5] * nd + bhi.y;
    h[6] = a0[6] * nd + bhi.z; h[7] = a0[7] * nd + bhi.w;
    if (RELU) {
#pragma unroll
        for (int j = 0; j < 8; ++j) h[j] = fmaxf(h[j], 0.f);
    }
    if (g == 0) {
        float4 o0 = {h[0], h[1], h[2], h[3]};
        float4 o1 = {h[4], h[5], h[6], h[7]};
        *(float4*)(out + (size_t)node * D + (c << 3)) = o0;
        *(float4*)(out + (size_t)node * D + (c << 3) + 4) = o1;
    }
}

// ---------------- launcher ----------------
extern "C" void kernel_launch(void* const* d_in, const int* in_sizes, int n_in,
                              void* d_out, int out_size, void* d_ws, size_t ws_size,
                              hipStream_t stream) {
    const float* x  = (const float*)d_in[0];
    const int* src  = (const int*)d_in[1];
    const int* dst  = (const int*)d_in[2];
    const float* W1 = (const float*)d_in[3];
    const float* b1 = (const float*)d_in[4];
    const float* W2 = (const float*)d_in[5];
    const float* b2 = (const float*)d_in[6];
    float* out = (float*)d_out;

    size_t off = 0;
    auto alloc = [&](size_t bytes) -> void* {
        void* p = (char*)d_ws + off;
        off += (bytes + 255) & ~(size_t)255;
        return p;
    };
    int* row_ptr  = (int*)alloc((size_t)(NN + 1) * 4);
    float* nsrc   = (float*)alloc((size_t)NN * 4);
    float* ndst   = (float*)alloc((size_t)NN * 4);
    int* gcurD    = (int*)alloc((size_t)(NBD + NBS) * 4);
    int* esrc     = (int*)alloc((size_t)NE * 4);                 // 6.4 MB
    _Float16* t_h = (_Float16*)alloc((size_t)NN * D * 2);        // 12.8 MB
    float* h1     = (float*)alloc((size_t)NN * D * 4);           // 25.6 MB
    (void)ws_size;
    int* gcurS = gcurD + NBD;

    // prep scratch aliases h1 (dead until aggregate1 writes it):
    // pbuf 196*10240*4 = 8.0MB | qloc 391*5120 = 2.0MB  -> 10MB < 25.6MB
    int* pbuf = (int*)h1;
    unsigned char* qloc = (unsigned char*)(pbuf + (size_t)NBD * CAPD);

    hipMemsetAsync(gcurD, 0, (size_t)(NBD + NBS) * 4, stream);

    partition_tf1_kernel<<<KB + TFB, PTB, 0, stream>>>(src, dst, gcurD, gcurS,
                                                       pbuf, qloc, x, W1, t_h);
    finalize_kernel<<<NBD + NBS, PTB, 0, stream>>>(pbuf, qloc, gcurD, gcurS,
                                                   row_ptr, nsrc, ndst, esrc);

    int ag_blocks = 12500;   // 4 waves/block x 2 nodes/wave = 8 nodes/block, exact
    aggregate_kernel<1, 1><<<ag_blocks, 256, 0, stream>>>(t_h, row_ptr, esrc, nsrc, ndst, b1, h1);
    transform_kernel<<<TFB, PTB, 0, stream>>>(h1, W2, nsrc, t_h);
    aggregate_kernel<0, 0><<<ag_blocks, 256, 0, stream>>>(t_h, row_ptr, esrc, nsrc, ndst, b2, out);
}

// Round 9
// 233.034 us; speedup vs baseline: 1.2488x; 1.0168x over previous
//
#include <hip/hip_runtime.h>
#include <math.h>

#define NN 100000
#define NE 1600000
#define D 64
#define NQ (NE / 4)

#define NBD 196                     // dst buckets, width 512 (dst>>9)
#define NBS 391                     // src buckets, width 256 (src>>8)

#define KB 500                      // partition blocks (both sides per block)
#define QPB (NQ / KB)               // 800 int4 quads per block (exact)
#define CAPD 44                     // dst cell cap, ints  (lambda 16.3, +6.9s, 1e-6 agg)
#define CAPS 36                     // src cell cap, bytes (lambda 8.2,  +9.4s, 2e-6 agg)
#define NWD (NBD * CAPD)            // 8624 staged dst words per block
#define NWS (NBS * CAPS / 4)        // 3519 staged src words per block (36 = 4*9)
#define ESCAP 8704                  // esrc LDS stage cap (bucket lambda 8192, +5.7 sigma)
#define PTB 512
#define TFB 782                     // transform blocks: 128 nodes each (782*128=100096)

typedef _Float16 h4v __attribute__((ext_vector_type(4)));
typedef _Float16 h8v __attribute__((ext_vector_type(8)));

// ============ tiled transform core (r7/r8-proven): 64-node tile, 4 waves ==============
__device__ __forceinline__ void tile_tf(
    const float* __restrict__ in, const float* __restrict__ W,
    const float* __restrict__ scale, _Float16* __restrict__ out,
    float* xT, int tileBase, int lt /*0..255*/)
{
    {
        int c4 = (lt & 15) << 2;
        int r0 = lt >> 4;
#pragma unroll
        for (int p = 0; p < 4; ++p) {
            int r = r0 + (p << 4);
            int node = tileBase + r;
            int nl = node < NN ? node : NN - 1;
            float4 v = *(const float4*)(in + (size_t)nl * D + c4);
            xT[(c4 + 0) * 64 + (r ^ c4)] = v.x;
            xT[(c4 + 1) * 64 + (r ^ c4)] = v.y;
            xT[(c4 + 2) * 64 + (r ^ c4)] = v.z;
            xT[(c4 + 3) * 64 + (r ^ c4)] = v.w;
        }
    }
    __syncthreads();
    int lane = lt & 63;
    int w = lt >> 6;
    int m0 = (lane >> 2) << 2;
    int nc = (w << 4) + ((lane & 3) << 2);
    float4 a0 = {0,0,0,0}, a1 = {0,0,0,0}, a2 = {0,0,0,0}, a3 = {0,0,0,0};
#pragma unroll 8
    for (int k = 0; k < 64; ++k) {
        int P = k & 60;
        float4 xa = *(const float4*)(xT + k * 64 + (m0 ^ P));
        float4 wv = *(const float4*)(W + k * D + nc);
        a0.x += xa.x * wv.x; a0.y += xa.x * wv.y; a0.z += xa.x * wv.z; a0.w += xa.x * wv.w;
        a1.x += xa.y * wv.x; a1.y += xa.y * wv.y; a1.z += xa.y * wv.z; a1.w += xa.y * wv.w;
        a2.x += xa.z * wv.x; a2.y += xa.z * wv.y; a2.z += xa.z * wv.z; a2.w += xa.z * wv.w;
        a3.x += xa.w * wv.x; a3.y += xa.w * wv.y; a3.z += xa.w * wv.z; a3.w += xa.w * wv.w;
    }
    float4 acc[4] = {a0, a1, a2, a3};
#pragma unroll
    for (int j = 0; j < 4; ++j) {
        int node = tileBase + m0 + j;
        if (node < NN) {
            float sc = scale ? scale[node] : 1.0f;
            h4v o;
            o[0] = (_Float16)(acc[j].x * sc); o[1] = (_Float16)(acc[j].y * sc);
            o[2] = (_Float16)(acc[j].z * sc); o[3] = (_Float16)(acc[j].w * sc);
            *(h4v*)(out + (size_t)node * D + nc) = o;
        }
    }
}

// ---------------- K1 (fused): blocks [0,KB) partition | [KB,KB+TFB) transform1 --------
// LDS-STAGED partition: entries scatter into LDS staging cells (per-wave-instruction
// cost), then flush to global as coalesced bursts. Removes ALL per-lane scattered
// global stores — the invariant ~46us across r0/r4/r5/r7/r8 matches the scatter-store
// transaction drain (~12.8K lane-transactions/block), not LDS atomics or cursors.
// Deterministic slots: cell (bucket i, block b) at (i*KB+b)*CAP; no global cursor
// atomics (r2's regression mechanism), no memset.
// LDS union layout (bytes): [0,34496) stageD ints | [34496,35280) hD | [35280,36844) hS
// | [36844,50920) stageS bytes. Transform1 aliases first 32KB as xT[2][4096].
__global__ __launch_bounds__(PTB) void partition_tf1_kernel(
    const int* __restrict__ src, const int* __restrict__ dst,
    int* __restrict__ cntD, int* __restrict__ cntS,
    int* __restrict__ pbuf, unsigned char* __restrict__ qloc,
    const float* __restrict__ x, const float* __restrict__ W1,
    _Float16* __restrict__ t_h)
{
    __shared__ __align__(16) char smem[50944];
    int t = threadIdx.x, b = blockIdx.x;
    if (b >= KB) {
        int half = t >> 8;
        int lt = t & 255;
        tile_tf(x, W1, (const float*)0, t_h,
                (float*)smem + half * (64 * 64), (b - KB) * 128 + half * 64, lt);
        return;
    }
    int* stageD = (int*)smem;                       // 8624 ints
    int* hD = (int*)(smem + 34496);                 // 196 cursors (index into stageD)
    int* hS = (int*)(smem + 35280);                 // 391 cursors (byte idx into stageS)
    unsigned char* stageS = (unsigned char*)(smem + 36844);   // 14076 bytes
    for (int i = t; i < NBD; i += PTB) hD[i] = i * CAPD;
    for (int i = t; i < NBS; i += PTB) hS[i] = i * CAPS;
    __syncthreads();
    const int4* s4 = (const int4*)src + (size_t)b * QPB;
    const int4* d4 = (const int4*)dst + (size_t)b * QPB;
    for (int i = t; i < QPB; i += PTB) {
        int4 a = s4[i], d = d4[i];
        int p;
        p = atomicAdd(&hD[d.x >> 9], 1); stageD[p] = ((d.x & 511) << 17) | a.x;
        p = atomicAdd(&hD[d.y >> 9], 1); stageD[p] = ((d.y & 511) << 17) | a.y;
        p = atomicAdd(&hD[d.z >> 9], 1); stageD[p] = ((d.z & 511) << 17) | a.z;
        p = atomicAdd(&hD[d.w >> 9], 1); stageD[p] = ((d.w & 511) << 17) | a.w;
        p = atomicAdd(&hS[a.x >> 8], 1); stageS[p] = (unsigned char)(a.x & 255);
        p = atomicAdd(&hS[a.y >> 8], 1); stageS[p] = (unsigned char)(a.y & 255);
        p = atomicAdd(&hS[a.z >> 8], 1); stageS[p] = (unsigned char)(a.z & 255);
        p = atomicAdd(&hS[a.w >> 8], 1); stageS[p] = (unsigned char)(a.w & 255);
    }
    __syncthreads();
    // ---- coalesced flush: pbuf cells (full cap; garbage beyond cnt is never read) ----
    for (int i = t; i < NWD; i += PTB) {
        int bkt = i / CAPD, slot = i - bkt * CAPD;
        pbuf[((size_t)bkt * KB + b) * CAPD + slot] = stageD[i];
    }
    const int* stageS_w = (const int*)(smem + 36844);
    int* qloc_w = (int*)qloc;
    for (int i = t; i < NWS; i += PTB) {
        int bkt = i / 9, sw = i - bkt * 9;          // 9 words per 36B cell
        qloc_w[((size_t)bkt * KB + b) * 9 + sw] = stageS_w[i];
    }
    for (int i = t; i < NBD; i += PTB) cntD[i * KB + b] = hD[i] - i * CAPD;
    for (int i = t; i < NBS; i += PTB) cntS[i * KB + b] = hS[i] - i * CAPS;
}

// ---------------- K2a: per-bucket totals ----------------
__global__ __launch_bounds__(256) void scan1_kernel(const int* __restrict__ cntD,
                                                    int* __restrict__ btot) {
    int B = blockIdx.x, t = threadIdx.x;
    __shared__ int ps[4];
    int s = 0;
    for (int j = t; j < KB; j += 256) s += cntD[B * KB + j];
    for (int o = 32; o > 0; o >>= 1) s += __shfl_xor(s, o, 64);
    if ((t & 63) == 0) ps[t >> 6] = s;
    __syncthreads();
    if (t == 0) btot[B] = ps[0] + ps[1] + ps[2] + ps[3];
}

// ---------------- K2b: exclusive prefix over bucket totals ----------------
__global__ __launch_bounds__(256) void scan2_kernel(const int* __restrict__ btot,
                                                    int* __restrict__ rowbase,
                                                    int* __restrict__ row_ptr) {
    __shared__ int tot[256];
    int t = threadIdx.x;
    tot[t] = (t < NBD) ? btot[t] : 0;
    __syncthreads();
    if (t < 64) {
        int v[4];
        int sum = 0;
#pragma unroll
        for (int j = 0; j < 4; ++j) { v[j] = tot[t * 4 + j]; sum += v[j]; }
        int incl = sum;
        for (int o = 1; o < 64; o <<= 1) {
            int u = __shfl_up(incl, o, 64);
            if (t >= o) incl += u;
        }
        int run = incl - sum;
#pragma unroll
        for (int j = 0; j < 4; ++j) { rowbase[t * 4 + j] = run; run += v[j]; }
    }
    if (t == 255) row_ptr[NN] = NE;
}

// ---------------- K3: finalize — LDS-staged esrc, coalesced flush ----------------
// dst block B: histogram 500 ragged runs (16-lane segments, 64B coalesced reads),
// prefix -> row_ptr/ndst, scatter into LDS stage (LDS atomic + LDS write), then
// contiguous flush esrc[beg..beg+cnt). No scattered global stores.
__global__ __launch_bounds__(PTB) void finalize_kernel(
    const int* __restrict__ pbuf, const unsigned char* __restrict__ qloc,
    const int* __restrict__ cntD, const int* __restrict__ cntS,
    const int* __restrict__ rowbase, const int* __restrict__ btot,
    int* __restrict__ row_ptr, float* __restrict__ nsrc,
    float* __restrict__ ndst, int* __restrict__ esrc)
{
    int B = blockIdx.x, t = threadIdx.x;
    int lane = t & 63, w = t >> 6;
    if (B >= NBD) {
        // ---- src side: out-degree histogram over 500 byte-runs (8-lane segments) ----
        int q = B - NBD;
        __shared__ int h[256];
        __shared__ int cs[KB];
        if (t < 256) h[t] = 0;
        if (t < KB) cs[t] = cntS[q * KB + t];
        __syncthreads();
        for (int r0 = 0; r0 < KB; r0 += 64) {
            int r = r0 + (w << 3) + (lane >> 3);
            if (r < KB) {
                int c = cs[r];
                const unsigned char* run = qloc + ((size_t)q * KB + r) * CAPS;
                for (int k = lane & 7; k < c; k += 8) atomicAdd(&h[run[k]], 1);
            }
        }
        __syncthreads();
        if (t < 256) {
            int n = (q << 8) + t;
            if (n < NN) nsrc[n] = 1.0f / sqrtf(fmaxf((float)h[t], 1.0f));
        }
        return;
    }
    __shared__ int fh[512], fcur[512];
    __shared__ int cl[KB];
    __shared__ int stage[ESCAP];
    if (t < KB) cl[t] = cntD[B * KB + t];
    for (int i = t; i < 512; i += PTB) fh[i] = 0;
    __syncthreads();
    int beg = rowbase[B];
    // ---- histogram pass: 16-lane segments, 4 segs/wave, 32 runs per sweep ----
    for (int r0 = 0; r0 < KB; r0 += 32) {
        int r = r0 + (w << 2) + (lane >> 4);
        if (r < KB) {
            int c = cl[r];
            const int* run = pbuf + ((size_t)B * KB + r) * CAPD;
            for (int k = lane & 15; k < c; k += 16) atomicAdd(&fh[run[k] >> 17], 1);
        }
    }
    __syncthreads();
    if (w == 0) {
        int v[8];
        int s = 0;
#pragma unroll
        for (int j = 0; j < 8; ++j) { v[j] = fh[lane * 8 + j]; s += v[j]; }
        int incl = s;
        for (int o = 1; o < 64; o <<= 1) {
            int u = __shfl_up(incl, o, 64);
            if (lane >= o) incl += u;
        }
        int run = incl - s;
#pragma unroll
        for (int j = 0; j < 8; ++j) {
            int bin = lane * 8 + j;
            fcur[bin] = run;
            int n = (B << 9) + bin;
            if (n < NN) {
                row_ptr[n] = beg + run;
                ndst[n] = 1.0f / sqrtf(fmaxf((float)v[j], 1.0f));
            }
            run += v[j];
        }
    }
    __syncthreads();
    // ---- scatter into LDS stage ----
    for (int r0 = 0; r0 < KB; r0 += 32) {
        int r = r0 + (w << 2) + (lane >> 4);
        if (r < KB) {
            int c = cl[r];
            const int* run = pbuf + ((size_t)B * KB + r) * CAPD;
            for (int k = lane & 15; k < c; k += 16) {
                int v = run[k];
                int p = atomicAdd(&fcur[v >> 17], 1);
                stage[p] = v & 0x1FFFF;
            }
        }
    }
    __syncthreads();
    // ---- coalesced flush ----
    int cnt = btot[B];
    for (int i = t; i < cnt; i += PTB) esrc[beg + i] = stage[i];
}

// ---------------- transform layer 2: t[v] = fp16( nsrc[v] * (h1[v] @ W2) ) ----------
__global__ __launch_bounds__(PTB) void transform_kernel(const float* __restrict__ xin,
                                                        const float* __restrict__ W,
                                                        const float* __restrict__ nsrc,
                                                        _Float16* __restrict__ out) {
    __shared__ float smem[2 * 64 * 64];
    int t = threadIdx.x;
    int half = t >> 8;
    int lt = t & 255;
    tile_tf(xin, W, nsrc, out, smem + half * (64 * 64),
            blockIdx.x * 128 + half * 64, lt);
}

// ---------------- aggregation (r8-proven): 2 nodes/wave, 4 chains/wave ----------------
template<int RELU, int USE_NSRC>
__global__ __launch_bounds__(256) void aggregate_kernel(const _Float16* __restrict__ t,
                                                        const int* __restrict__ row_ptr,
                                                        const int* __restrict__ esrc,
                                                        const float* __restrict__ nsrc,
                                                        const float* __restrict__ ndst,
                                                        const float* __restrict__ bias,
                                                        float* __restrict__ out) {
    int wid = (blockIdx.x * 256 + threadIdx.x) >> 6;
    int lane = threadIdx.x & 63;
    int half = lane >> 5;
    int l5 = lane & 31;
    int g = l5 >> 3, c = l5 & 7;
    int node = wid * 2 + half;
    if (node >= NN) return;
    int beg = row_ptr[node], end = row_ptr[node + 1];
    float a0[8] = {0,0,0,0,0,0,0,0};
    float a1[8] = {0,0,0,0,0,0,0,0};
    int i = beg;
    for (; i + 8 <= end; i += 8) {
        int s0 = esrc[i + g];
        int s1 = esrc[i + 4 + g];
        float ns0 = USE_NSRC ? nsrc[s0] : 1.0f;
        float ns1 = USE_NSRC ? nsrc[s1] : 1.0f;
        h8v v0 = *(const h8v*)(t + (size_t)s0 * D + (c << 3));
        h8v v1 = *(const h8v*)(t + (size_t)s1 * D + (c << 3));
#pragma unroll
        for (int j = 0; j < 8; ++j) {
            if (USE_NSRC) { a0[j] += (float)v0[j] * ns0; a1[j] += (float)v1[j] * ns1; }
            else          { a0[j] += (float)v0[j];       a1[j] += (float)v1[j]; }
        }
    }
    for (; i < end; i += 4) {
        int e = i + g;
        if (e < end) {
            int s = esrc[e];
            float ns = USE_NSRC ? nsrc[s] : 1.0f;
            h8v v = *(const h8v*)(t + (size_t)s * D + (c << 3));
#pragma unroll
            for (int j = 0; j < 8; ++j) {
                if (USE_NSRC) a0[j] += (float)v[j] * ns;
                else          a0[j] += (float)v[j];
            }
        }
    }
#pragma unroll
    for (int j = 0; j < 8; ++j) a0[j] += a1[j];
#pragma unroll
    for (int j = 0; j < 8; ++j) {
        a0[j] += __shfl_xor(a0[j], 8, 64);
        a0[j] += __shfl_xor(a0[j], 16, 64);
    }
    float nd = ndst[node];
    float4 blo = *(const float4*)(bias + (c << 3));
    float4 bhi = *(const float4*)(bias + (c << 3) + 4);
    float h[8];
    h[0] = a0[0] * nd + blo.x; h[1] = a0[1] * nd + blo.y;
    h[2] = a0[2] * nd + blo.z; h[3] = a0[3] * nd + blo.w;
    h[4] = a0[4] * nd + bhi.x; h[5] = a0[5] * nd + bhi.y;
    h[6] = a0[6] * nd + bhi.z; h[7] = a0[7] * nd + bhi.w;
    if (RELU) {
#pragma unroll
        for (int j = 0; j < 8; ++j) h[j] = fmaxf(h[j], 0.f);
    }
    if (g == 0) {
        float4 o0 = {h[0], h[1], h[2], h[3]};
        float4 o1 = {h[4], h[5], h[6], h[7]};
        *(float4*)(out + (size_t)node * D + (c << 3)) = o0;
        *(float4*)(out + (size_t)node * D + (c << 3) + 4) = o1;
    }
}

// ---------------- launcher ----------------
extern "C" void kernel_launch(void* const* d_in, const int* in_sizes, int n_in,
                              void* d_out, int out_size, void* d_ws, size_t ws_size,
                              hipStream_t stream) {
    const float* x  = (const float*)d_in[0];
    const int* src  = (const int*)d_in[1];
    const int* dst  = (const int*)d_in[2];
    const float* W1 = (const float*)d_in[3];
    const float* b1 = (const float*)d_in[4];
    const float* W2 = (const float*)d_in[5];
    const float* b2 = (const float*)d_in[6];
    float* out = (float*)d_out;

    size_t off = 0;
    auto alloc = [&](size_t bytes) -> void* {
        void* p = (char*)d_ws + off;
        off += (bytes + 255) & ~(size_t)255;
        return p;
    };
    int* row_ptr  = (int*)alloc((size_t)(NN + 1) * 4);
    float* nsrc   = (float*)alloc((size_t)NN * 4);
    float* ndst   = (float*)alloc((size_t)NN * 4);
    int* rowbase  = (int*)alloc((size_t)256 * 4);
    int* btot     = (int*)alloc((size_t)256 * 4);
    int* cntD     = (int*)alloc((size_t)NBD * KB * 4);           // 392 KB
    int* cntS     = (int*)alloc((size_t)NBS * KB * 4);           // 782 KB
    int* esrc     = (int*)alloc((size_t)NE * 4);                 // 6.4 MB
    _Float16* t_h = (_Float16*)alloc((size_t)NN * D * 2);        // 12.8 MB
    float* h1     = (float*)alloc((size_t)NN * D * 4);           // 25.6 MB
    (void)ws_size;

    // prep scratch aliases h1 (dead until aggregate1 writes it):
    // pbuf 196*500*44*4 = 17.2MB | qloc 391*500*36 = 7.0MB -> 24.2MB < 25.6MB
    int* pbuf = (int*)h1;
    unsigned char* qloc = (unsigned char*)(pbuf + (size_t)NBD * KB * CAPD);

    partition_tf1_kernel<<<KB + TFB, PTB, 0, stream>>>(src, dst, cntD, cntS,
                                                       pbuf, qloc, x, W1, t_h);
    scan1_kernel<<<NBD, 256, 0, stream>>>(cntD, btot);
    scan2_kernel<<<1, 256, 0, stream>>>(btot, rowbase, row_ptr);
    finalize_kernel<<<NBD + NBS, PTB, 0, stream>>>(pbuf, qloc, cntD, cntS, rowbase,
                                                   btot, row_ptr, nsrc, ndst, esrc);

    int ag_blocks = 12500;
    aggregate_kernel<1, 1><<<ag_blocks, 256, 0, stream>>>(t_h, row_ptr, esrc, nsrc, ndst, b1, h1);
    transform_kernel<<<TFB, PTB, 0, stream>>>(h1, W2, nsrc, t_h);
    aggregate_kernel<0, 0><<<ag_blocks, 256, 0, stream>>>(t_h, row_ptr, esrc, nsrc, ndst, b2, out);
}

// Round 10
// 230.339 us; speedup vs baseline: 1.2634x; 1.0117x over previous
//
#include <hip/hip_runtime.h>
#include <math.h>

#define NN 100000
#define NE 1600000
#define D 64
#define NQ (NE / 4)

#define NBD 196                     // dst buckets, width 512 (dst>>9)
#define NBS 391                     // src buckets, width 256 (src>>8)

#define KB 500                      // partition blocks (both sides per block)
#define QPB (NQ / KB)               // 800 int4 quads per block (exact)
#define CAPD 44                     // dst cell cap, ints  (lambda 16.3, +6.9s, 1e-6 agg)
#define CAPS 36                     // src cell cap, bytes (lambda 8.2,  +9.4s, 2e-6 agg)
#define NWD (NBD * CAPD)            // 8624 staged dst words per block
#define NWS (NBS * CAPS / 4)        // 3519 staged src words per block (36 = 4*9)
#define ESCAP 8704                  // esrc LDS stage cap (bucket lambda 8192, +5.7 sigma)
#define PTB 512
#define TFB 782                     // transform blocks: 128 nodes each (782*128=100096)

typedef _Float16 h4v __attribute__((ext_vector_type(4)));
typedef _Float16 h8v __attribute__((ext_vector_type(8)));

// ============ tiled transform core (r7/r8-proven): 64-node tile, 4 waves ==============
__device__ __forceinline__ void tile_tf(
    const float* __restrict__ in, const float* __restrict__ W,
    const float* __restrict__ scale, _Float16* __restrict__ out,
    float* xT, int tileBase, int lt /*0..255*/)
{
    {
        int c4 = (lt & 15) << 2;
        int r0 = lt >> 4;
#pragma unroll
        for (int p = 0; p < 4; ++p) {
            int r = r0 + (p << 4);
            int node = tileBase + r;
            int nl = node < NN ? node : NN - 1;
            float4 v = *(const float4*)(in + (size_t)nl * D + c4);
            xT[(c4 + 0) * 64 + (r ^ c4)] = v.x;
            xT[(c4 + 1) * 64 + (r ^ c4)] = v.y;
            xT[(c4 + 2) * 64 + (r ^ c4)] = v.z;
            xT[(c4 + 3) * 64 + (r ^ c4)] = v.w;
        }
    }
    __syncthreads();
    int lane = lt & 63;
    int w = lt >> 6;
    int m0 = (lane >> 2) << 2;
    int nc = (w << 4) + ((lane & 3) << 2);
    float4 a0 = {0,0,0,0}, a1 = {0,0,0,0}, a2 = {0,0,0,0}, a3 = {0,0,0,0};
#pragma unroll 8
    for (int k = 0; k < 64; ++k) {
        int P = k & 60;
        float4 xa = *(const float4*)(xT + k * 64 + (m0 ^ P));
        float4 wv = *(const float4*)(W + k * D + nc);
        a0.x += xa.x * wv.x; a0.y += xa.x * wv.y; a0.z += xa.x * wv.z; a0.w += xa.x * wv.w;
        a1.x += xa.y * wv.x; a1.y += xa.y * wv.y; a1.z += xa.y * wv.z; a1.w += xa.y * wv.w;
        a2.x += xa.z * wv.x; a2.y += xa.z * wv.y; a2.z += xa.z * wv.z; a2.w += xa.z * wv.w;
        a3.x += xa.w * wv.x; a3.y += xa.w * wv.y; a3.z += xa.w * wv.z; a3.w += xa.w * wv.w;
    }
    float4 acc[4] = {a0, a1, a2, a3};
#pragma unroll
    for (int j = 0; j < 4; ++j) {
        int node = tileBase + m0 + j;
        if (node < NN) {
            float sc = scale ? scale[node] : 1.0f;
            h4v o;
            o[0] = (_Float16)(acc[j].x * sc); o[1] = (_Float16)(acc[j].y * sc);
            o[2] = (_Float16)(acc[j].z * sc); o[3] = (_Float16)(acc[j].w * sc);
            *(h4v*)(out + (size_t)node * D + nc) = o;
        }
    }
}

// ---------------- K1 (fused): blocks [0,KB) partition | [KB,KB+TFB) transform1 --------
// LDS-staged deterministic-slot partition (r9), coalesced flush, no global cursors.
__global__ __launch_bounds__(PTB) void partition_tf1_kernel(
    const int* __restrict__ src, const int* __restrict__ dst,
    int* __restrict__ cntD, int* __restrict__ cntS,
    int* __restrict__ pbuf, unsigned char* __restrict__ qloc,
    const float* __restrict__ x, const float* __restrict__ W1,
    _Float16* __restrict__ t_h)
{
    __shared__ __align__(16) char smem[50944];
    int t = threadIdx.x, b = blockIdx.x;
    if (b >= KB) {
        int half = t >> 8;
        int lt = t & 255;
        tile_tf(x, W1, (const float*)0, t_h,
                (float*)smem + half * (64 * 64), (b - KB) * 128 + half * 64, lt);
        return;
    }
    int* stageD = (int*)smem;                       // 8624 ints
    int* hD = (int*)(smem + 34496);                 // 196 cursors
    int* hS = (int*)(smem + 35280);                 // 391 cursors
    unsigned char* stageS = (unsigned char*)(smem + 36844);   // 14076 bytes
    for (int i = t; i < NBD; i += PTB) hD[i] = i * CAPD;
    for (int i = t; i < NBS; i += PTB) hS[i] = i * CAPS;
    __syncthreads();
    const int4* s4 = (const int4*)src + (size_t)b * QPB;
    const int4* d4 = (const int4*)dst + (size_t)b * QPB;
    for (int i = t; i < QPB; i += PTB) {
        int4 a = s4[i], d = d4[i];
        int p;
        p = atomicAdd(&hD[d.x >> 9], 1); stageD[p] = ((d.x & 511) << 17) | a.x;
        p = atomicAdd(&hD[d.y >> 9], 1); stageD[p] = ((d.y & 511) << 17) | a.y;
        p = atomicAdd(&hD[d.z >> 9], 1); stageD[p] = ((d.z & 511) << 17) | a.z;
        p = atomicAdd(&hD[d.w >> 9], 1); stageD[p] = ((d.w & 511) << 17) | a.w;
        p = atomicAdd(&hS[a.x >> 8], 1); stageS[p] = (unsigned char)(a.x & 255);
        p = atomicAdd(&hS[a.y >> 8], 1); stageS[p] = (unsigned char)(a.y & 255);
        p = atomicAdd(&hS[a.z >> 8], 1); stageS[p] = (unsigned char)(a.z & 255);
        p = atomicAdd(&hS[a.w >> 8], 1); stageS[p] = (unsigned char)(a.w & 255);
    }
    __syncthreads();
    for (int i = t; i < NWD; i += PTB) {
        int bkt = i / CAPD, slot = i - bkt * CAPD;
        pbuf[((size_t)bkt * KB + b) * CAPD + slot] = stageD[i];
    }
    const int* stageS_w = (const int*)(smem + 36844);
    int* qloc_w = (int*)qloc;
    for (int i = t; i < NWS; i += PTB) {
        int bkt = i / 9, sw = i - bkt * 9;
        qloc_w[((size_t)bkt * KB + b) * 9 + sw] = stageS_w[i];
    }
    for (int i = t; i < NBD; i += PTB) cntD[i * KB + b] = hD[i] - i * CAPD;
    for (int i = t; i < NBS; i += PTB) cntS[i * KB + b] = hS[i] - i * CAPS;
}

// ---------------- K2: per-bucket totals ----------------
__global__ __launch_bounds__(256) void scan1_kernel(const int* __restrict__ cntD,
                                                    int* __restrict__ btot) {
    int B = blockIdx.x, t = threadIdx.x;
    __shared__ int ps[4];
    int s = 0;
    for (int j = t; j < KB; j += 256) s += cntD[B * KB + j];
    for (int o = 32; o > 0; o >>= 1) s += __shfl_xor(s, o, 64);
    if ((t & 63) == 0) ps[t >> 6] = s;
    __syncthreads();
    if (t == 0) btot[B] = ps[0] + ps[1] + ps[2] + ps[3];
}

// ---------------- K3: finalize — in-block prefix (scan2 merged), LDS-staged esrc ------
__global__ __launch_bounds__(PTB) void finalize_kernel(
    const int* __restrict__ pbuf, const unsigned char* __restrict__ qloc,
    const int* __restrict__ cntD, const int* __restrict__ cntS,
    const int* __restrict__ btot,
    int* __restrict__ row_ptr, float* __restrict__ nsrc,
    float* __restrict__ ndst, int* __restrict__ esrc)
{
    int B = blockIdx.x, t = threadIdx.x;
    int lane = t & 63, w = t >> 6;
    if (B >= NBD) {
        // ---- src side: out-degree histogram over 500 byte-runs (8-lane segments) ----
        int q = B - NBD;
        __shared__ int h[256];
        __shared__ int cs[KB];
        if (t < 256) h[t] = 0;
        if (t < KB) cs[t] = cntS[q * KB + t];
        __syncthreads();
        for (int r0 = 0; r0 < KB; r0 += 64) {
            int r = r0 + (w << 3) + (lane >> 3);
            if (r < KB) {
                int c = cs[r];
                const unsigned char* run = qloc + ((size_t)q * KB + r) * CAPS;
                for (int k = lane & 7; k < c; k += 8) atomicAdd(&h[run[k]], 1);
            }
        }
        __syncthreads();
        if (t < 256) {
            int n = (q << 8) + t;
            if (n < NN) nsrc[n] = 1.0f / sqrtf(fmaxf((float)h[t], 1.0f));
        }
        return;
    }
    __shared__ int fh[512], fcur[512];
    __shared__ int cl[KB];
    __shared__ int stage[ESCAP];
    __shared__ int sbeg;
    if (t < KB) cl[t] = cntD[B * KB + t];
    for (int i = t; i < 512; i += PTB) fh[i] = 0;
    if (w == 0) {                                   // scan2 merged: prefix of btot[0..B)
        int s = 0;
        for (int j = lane; j < B; j += 64) s += btot[j];
        for (int o = 32; o > 0; o >>= 1) s += __shfl_xor(s, o, 64);
        if (lane == 0) sbeg = s;
    }
    if (B == 0 && t == 128) row_ptr[NN] = NE;
    __syncthreads();
    int beg = sbeg;
    // ---- histogram pass: 16-lane segments over 500 ragged runs ----
    for (int r0 = 0; r0 < KB; r0 += 32) {
        int r = r0 + (w << 2) + (lane >> 4);
        if (r < KB) {
            int c = cl[r];
            const int* run = pbuf + ((size_t)B * KB + r) * CAPD;
            for (int k = lane & 15; k < c; k += 16) atomicAdd(&fh[run[k] >> 17], 1);
        }
    }
    __syncthreads();
    if (w == 0) {
        int v[8];
        int s = 0;
#pragma unroll
        for (int j = 0; j < 8; ++j) { v[j] = fh[lane * 8 + j]; s += v[j]; }
        int incl = s;
        for (int o = 1; o < 64; o <<= 1) {
            int u = __shfl_up(incl, o, 64);
            if (lane >= o) incl += u;
        }
        int run = incl - s;
#pragma unroll
        for (int j = 0; j < 8; ++j) {
            int bin = lane * 8 + j;
            fcur[bin] = run;
            int n = (B << 9) + bin;
            if (n < NN) {
                row_ptr[n] = beg + run;
                ndst[n] = 1.0f / sqrtf(fmaxf((float)v[j], 1.0f));
            }
            run += v[j];
        }
    }
    __syncthreads();
    // ---- scatter into LDS stage ----
    for (int r0 = 0; r0 < KB; r0 += 32) {
        int r = r0 + (w << 2) + (lane >> 4);
        if (r < KB) {
            int c = cl[r];
            const int* run = pbuf + ((size_t)B * KB + r) * CAPD;
            for (int k = lane & 15; k < c; k += 16) {
                int v = run[k];
                int p = atomicAdd(&fcur[v >> 17], 1);
                stage[p] = v & 0x1FFFF;
            }
        }
    }
    __syncthreads();
    // ---- coalesced flush ----
    int cnt = btot[B];
    for (int i = t; i < cnt; i += PTB) esrc[beg + i] = stage[i];
}

// ---------------- transform layer 2: t[v] = fp16( nsrc[v] * (h1[v] @ W2) ) ----------
__global__ __launch_bounds__(PTB) void transform_kernel(const float* __restrict__ xin,
                                                        const float* __restrict__ W,
                                                        const float* __restrict__ nsrc,
                                                        _Float16* __restrict__ out) {
    __shared__ float smem[2 * 64 * 64];
    int t = threadIdx.x;
    int half = t >> 8;
    int lt = t & 255;
    tile_tf(xin, W, nsrc, out, smem + half * (64 * 64),
            blockIdx.x * 128 + half * 64, lt);
}

// ---------------- aggregation: 4 nodes/wave, 2 slots x 2 streams = 8 chains/wave ------
// r7->r8 (2->4 chains) gave +12%; arithmetic says still MLP-limited (17 cyc/edge vs
// ~2-9 cyc memory floor). 16-lane node groups: g=slot(2), c=ch-group(8); 8 lanes x 16B
// = full 128B row per slot (coalescing unchanged). Reduce: single xor(8).
template<int RELU, int USE_NSRC>
__global__ __launch_bounds__(256) void aggregate_kernel(const _Float16* __restrict__ t,
                                                        const int* __restrict__ row_ptr,
                                                        const int* __restrict__ esrc,
                                                        const float* __restrict__ nsrc,
                                                        const float* __restrict__ ndst,
                                                        const float* __restrict__ bias,
                                                        float* __restrict__ out) {
    int wid = (blockIdx.x * 256 + threadIdx.x) >> 6;
    int lane = threadIdx.x & 63;
    int quad = lane >> 4;               // node-in-wave 0..3
    int l4 = lane & 15;
    int g = l4 >> 3, c = l4 & 7;        // 2 edge slots x 8 channel-groups
    int node = wid * 4 + quad;
    if (node >= NN) return;
    int beg = row_ptr[node], end = row_ptr[node + 1];
    float a0[8] = {0,0,0,0,0,0,0,0};
    float a1[8] = {0,0,0,0,0,0,0,0};
    int i = beg;
    for (; i + 4 <= end; i += 4) {
        int s0 = esrc[i + g];
        int s1 = esrc[i + 2 + g];
        float ns0 = USE_NSRC ? nsrc[s0] : 1.0f;
        float ns1 = USE_NSRC ? nsrc[s1] : 1.0f;
        h8v v0 = *(const h8v*)(t + (size_t)s0 * D + (c << 3));
        h8v v1 = *(const h8v*)(t + (size_t)s1 * D + (c << 3));
#pragma unroll
        for (int j = 0; j < 8; ++j) {
            if (USE_NSRC) { a0[j] += (float)v0[j] * ns0; a1[j] += (float)v1[j] * ns1; }
            else          { a0[j] += (float)v0[j];       a1[j] += (float)v1[j]; }
        }
    }
    for (; i < end; i += 2) {
        int e = i + g;
        if (e < end) {
            int s = esrc[e];
            float ns = USE_NSRC ? nsrc[s] : 1.0f;
            h8v v = *(const h8v*)(t + (size_t)s * D + (c << 3));
#pragma unroll
            for (int j = 0; j < 8; ++j) {
                if (USE_NSRC) a0[j] += (float)v[j] * ns;
                else          a0[j] += (float)v[j];
            }
        }
    }
#pragma unroll
    for (int j = 0; j < 8; ++j) a0[j] += a1[j];
#pragma unroll
    for (int j = 0; j < 8; ++j) {
        a0[j] += __shfl_xor(a0[j], 8, 64);
    }
    float nd = ndst[node];
    float4 blo = *(const float4*)(bias + (c << 3));
    float4 bhi = *(const float4*)(bias + (c << 3) + 4);
    float h[8];
    h[0] = a0[0] * nd + blo.x; h[1] = a0[1] * nd + blo.y;
    h[2] = a0[2] * nd + blo.z; h[3] = a0[3] * nd + blo.w;
    h[4] = a0[4] * nd + bhi.x; h[5] = a0[5] * nd + bhi.y;
    h[6] = a0[6] * nd + bhi.z; h[7] = a0[7] * nd + bhi.w;
    if (RELU) {
#pragma unroll
        for (int j = 0; j < 8; ++j) h[j] = fmaxf(h[j], 0.f);
    }
    if (g == 0) {
        float4 o0 = {h[0], h[1], h[2], h[3]};
        float4 o1 = {h[4], h[5], h[6], h[7]};
        *(float4*)(out + (size_t)node * D + (c << 3)) = o0;
        *(float4*)(out + (size_t)node * D + (c << 3) + 4) = o1;
    }
}

// ---------------- launcher ----------------
extern "C" void kernel_launch(void* const* d_in, const int* in_sizes, int n_in,
                              void* d_out, int out_size, void* d_ws, size_t ws_size,
                              hipStream_t stream) {
    const float* x  = (const float*)d_in[0];
    const int* src  = (const int*)d_in[1];
    const int* dst  = (const int*)d_in[2];
    const float* W1 = (const float*)d_in[3];
    const float* b1 = (const float*)d_in[4];
    const float* W2 = (const float*)d_in[5];
    const float* b2 = (const float*)d_in[6];
    float* out = (float*)d_out;

    size_t off = 0;
    auto alloc = [&](size_t bytes) -> void* {
        void* p = (char*)d_ws + off;
        off += (bytes + 255) & ~(size_t)255;
        return p;
    };
    int* row_ptr  = (int*)alloc((size_t)(NN + 1) * 4);
    float* nsrc   = (float*)alloc((size_t)NN * 4);
    float* ndst   = (float*)alloc((size_t)NN * 4);
    int* btot     = (int*)alloc((size_t)256 * 4);
    int* cntD     = (int*)alloc((size_t)NBD * KB * 4);           // 392 KB
    int* cntS     = (int*)alloc((size_t)NBS * KB * 4);           // 782 KB
    int* esrc     = (int*)alloc((size_t)NE * 4);                 // 6.4 MB
    _Float16* t_h = (_Float16*)alloc((size_t)NN * D * 2);        // 12.8 MB
    float* h1     = (float*)alloc((size_t)NN * D * 4);           // 25.6 MB
    (void)ws_size;

    // prep scratch aliases h1 (dead until aggregate1 writes it):
    // pbuf 196*500*44*4 = 17.2MB | qloc 391*500*36 = 7.0MB -> 24.2MB < 25.6MB
    int* pbuf = (int*)h1;
    unsigned char* qloc = (unsigned char*)(pbuf + (size_t)NBD * KB * CAPD);

    partition_tf1_kernel<<<KB + TFB, PTB, 0, stream>>>(src, dst, cntD, cntS,
                                                       pbuf, qloc, x, W1, t_h);
    scan1_kernel<<<NBD, 256, 0, stream>>>(cntD, btot);
    finalize_kernel<<<NBD + NBS, PTB, 0, stream>>>(pbuf, qloc, cntD, cntS, btot,
                                                   row_ptr, nsrc, ndst, esrc);

    int ag_blocks = 6250;    // 4 waves/block x 4 nodes/wave = 16 nodes/block, exact
    aggregate_kernel<1, 1><<<ag_blocks, 256, 0, stream>>>(t_h, row_ptr, esrc, nsrc, ndst, b1, h1);
    transform_kernel<<<TFB, PTB, 0, stream>>>(h1, W2, nsrc, t_h);
    aggregate_kernel<0, 0><<<ag_blocks, 256, 0, stream>>>(t_h, row_ptr, esrc, nsrc, ndst, b2, out);
}

// Round 11
// 217.980 us; speedup vs baseline: 1.3350x; 1.0567x over previous
//
#include <hip/hip_runtime.h>
#include <math.h>

#define NN 100000
#define NE 1600000
#define D 64
#define NQ (NE / 4)

#define NBD 196                     // dst buckets, width 512 (dst>>9)
#define NBS 391                     // src buckets, width 256 (src>>8)

#define KB 500                      // partition blocks (both sides per block)
#define QPB (NQ / KB)               // 800 int4 quads per block (exact)
#define CAPD 44                     // dst cell cap, ints  (lambda 16.3, +6.9s, 1e-6 agg)
#define CAPS 36                     // src cell cap, bytes (lambda 8.2,  +9.4s, 2e-6 agg)
#define NWD (NBD * CAPD)            // 8624 staged dst words per block
#define NWS (NBS * CAPS / 4)        // 3519 staged src words per block (36 = 4*9)
#define ESCAP 8704                  // esrc LDS stage cap (bucket lambda 8192, +5.7 sigma)
#define PTB 512
#define TFB 782                     // tf1 blocks: 128 nodes each (782*128=100096)
#define AGTB 1563                   // fused agg+tf blocks: 64 nodes each (1563*64=100032)

typedef _Float16 h4v __attribute__((ext_vector_type(4)));
typedef _Float16 h8v __attribute__((ext_vector_type(8)));

// ============ tiled transform core (r7/r8-proven): 64-node tile, 4 waves ==============
__device__ __forceinline__ void tile_tf(
    const float* __restrict__ in, const float* __restrict__ W,
    const float* __restrict__ scale, _Float16* __restrict__ out,
    float* xT, int tileBase, int lt /*0..255*/)
{
    {
        int c4 = (lt & 15) << 2;
        int r0 = lt >> 4;
#pragma unroll
        for (int p = 0; p < 4; ++p) {
            int r = r0 + (p << 4);
            int node = tileBase + r;
            int nl = node < NN ? node : NN - 1;
            float4 v = *(const float4*)(in + (size_t)nl * D + c4);
            xT[(c4 + 0) * 64 + (r ^ c4)] = v.x;
            xT[(c4 + 1) * 64 + (r ^ c4)] = v.y;
            xT[(c4 + 2) * 64 + (r ^ c4)] = v.z;
            xT[(c4 + 3) * 64 + (r ^ c4)] = v.w;
        }
    }
    __syncthreads();
    int lane = lt & 63;
    int w = lt >> 6;
    int m0 = (lane >> 2) << 2;
    int nc = (w << 4) + ((lane & 3) << 2);
    float4 a0 = {0,0,0,0}, a1 = {0,0,0,0}, a2 = {0,0,0,0}, a3 = {0,0,0,0};
#pragma unroll 8
    for (int k = 0; k < 64; ++k) {
        int P = k & 60;
        float4 xa = *(const float4*)(xT + k * 64 + (m0 ^ P));
        float4 wv = *(const float4*)(W + k * D + nc);
        a0.x += xa.x * wv.x; a0.y += xa.x * wv.y; a0.z += xa.x * wv.z; a0.w += xa.x * wv.w;
        a1.x += xa.y * wv.x; a1.y += xa.y * wv.y; a1.z += xa.y * wv.z; a1.w += xa.y * wv.w;
        a2.x += xa.z * wv.x; a2.y += xa.z * wv.y; a2.z += xa.z * wv.z; a2.w += xa.z * wv.w;
        a3.x += xa.w * wv.x; a3.y += xa.w * wv.y; a3.z += xa.w * wv.z; a3.w += xa.w * wv.w;
    }
    float4 acc[4] = {a0, a1, a2, a3};
#pragma unroll
    for (int j = 0; j < 4; ++j) {
        int node = tileBase + m0 + j;
        if (node < NN) {
            float sc = scale ? scale[node] : 1.0f;
            h4v o;
            o[0] = (_Float16)(acc[j].x * sc); o[1] = (_Float16)(acc[j].y * sc);
            o[2] = (_Float16)(acc[j].z * sc); o[3] = (_Float16)(acc[j].w * sc);
            *(h4v*)(out + (size_t)node * D + nc) = o;
        }
    }
}

// ---------------- K1 (fused): blocks [0,KB) partition | [KB,KB+TFB) transform1 --------
// LDS-staged deterministic-slot partition (r9), coalesced flush, no global cursors.
__global__ __launch_bounds__(PTB) void partition_tf1_kernel(
    const int* __restrict__ src, const int* __restrict__ dst,
    int* __restrict__ cntD, int* __restrict__ cntS,
    int* __restrict__ pbuf, unsigned char* __restrict__ qloc,
    const float* __restrict__ x, const float* __restrict__ W1,
    _Float16* __restrict__ t_h)
{
    __shared__ __align__(16) char smem[50944];
    int t = threadIdx.x, b = blockIdx.x;
    if (b >= KB) {
        int half = t >> 8;
        int lt = t & 255;
        tile_tf(x, W1, (const float*)0, t_h,
                (float*)smem + half * (64 * 64), (b - KB) * 128 + half * 64, lt);
        return;
    }
    int* stageD = (int*)smem;                       // 8624 ints
    int* hD = (int*)(smem + 34496);                 // 196 cursors
    int* hS = (int*)(smem + 35280);                 // 391 cursors
    unsigned char* stageS = (unsigned char*)(smem + 36844);   // 14076 bytes
    for (int i = t; i < NBD; i += PTB) hD[i] = i * CAPD;
    for (int i = t; i < NBS; i += PTB) hS[i] = i * CAPS;
    __syncthreads();
    const int4* s4 = (const int4*)src + (size_t)b * QPB;
    const int4* d4 = (const int4*)dst + (size_t)b * QPB;
    for (int i = t; i < QPB; i += PTB) {
        int4 a = s4[i], d = d4[i];
        int p;
        p = atomicAdd(&hD[d.x >> 9], 1); stageD[p] = ((d.x & 511) << 17) | a.x;
        p = atomicAdd(&hD[d.y >> 9], 1); stageD[p] = ((d.y & 511) << 17) | a.y;
        p = atomicAdd(&hD[d.z >> 9], 1); stageD[p] = ((d.z & 511) << 17) | a.z;
        p = atomicAdd(&hD[d.w >> 9], 1); stageD[p] = ((d.w & 511) << 17) | a.w;
        p = atomicAdd(&hS[a.x >> 8], 1); stageS[p] = (unsigned char)(a.x & 255);
        p = atomicAdd(&hS[a.y >> 8], 1); stageS[p] = (unsigned char)(a.y & 255);
        p = atomicAdd(&hS[a.z >> 8], 1); stageS[p] = (unsigned char)(a.z & 255);
        p = atomicAdd(&hS[a.w >> 8], 1); stageS[p] = (unsigned char)(a.w & 255);
    }
    __syncthreads();
    for (int i = t; i < NWD; i += PTB) {
        int bkt = i / CAPD, slot = i - bkt * CAPD;
        pbuf[((size_t)bkt * KB + b) * CAPD + slot] = stageD[i];
    }
    const int* stageS_w = (const int*)(smem + 36844);
    int* qloc_w = (int*)qloc;
    for (int i = t; i < NWS; i += PTB) {
        int bkt = i / 9, sw = i - bkt * 9;
        qloc_w[((size_t)bkt * KB + b) * 9 + sw] = stageS_w[i];
    }
    for (int i = t; i < NBD; i += PTB) cntD[i * KB + b] = hD[i] - i * CAPD;
    for (int i = t; i < NBS; i += PTB) cntS[i * KB + b] = hS[i] - i * CAPS;
}

// ---------------- K2: per-bucket totals ----------------
__global__ __launch_bounds__(256) void scan1_kernel(const int* __restrict__ cntD,
                                                    int* __restrict__ btot) {
    int B = blockIdx.x, t = threadIdx.x;
    __shared__ int ps[4];
    int s = 0;
    for (int j = t; j < KB; j += 256) s += cntD[B * KB + j];
    for (int o = 32; o > 0; o >>= 1) s += __shfl_xor(s, o, 64);
    if ((t & 63) == 0) ps[t >> 6] = s;
    __syncthreads();
    if (t == 0) btot[B] = ps[0] + ps[1] + ps[2] + ps[3];
}

// ---------------- K3: finalize — in-block prefix, LDS-staged esrc (r10-proven) --------
__global__ __launch_bounds__(PTB) void finalize_kernel(
    const int* __restrict__ pbuf, const unsigned char* __restrict__ qloc,
    const int* __restrict__ cntD, const int* __restrict__ cntS,
    const int* __restrict__ btot,
    int* __restrict__ row_ptr, float* __restrict__ nsrc,
    float* __restrict__ ndst, int* __restrict__ esrc)
{
    int B = blockIdx.x, t = threadIdx.x;
    int lane = t & 63, w = t >> 6;
    if (B >= NBD) {
        int q = B - NBD;
        __shared__ int h[256];
        __shared__ int cs[KB];
        if (t < 256) h[t] = 0;
        if (t < KB) cs[t] = cntS[q * KB + t];
        __syncthreads();
        for (int r0 = 0; r0 < KB; r0 += 64) {
            int r = r0 + (w << 3) + (lane >> 3);
            if (r < KB) {
                int c = cs[r];
                const unsigned char* run = qloc + ((size_t)q * KB + r) * CAPS;
                for (int k = lane & 7; k < c; k += 8) atomicAdd(&h[run[k]], 1);
            }
        }
        __syncthreads();
        if (t < 256) {
            int n = (q << 8) + t;
            if (n < NN) nsrc[n] = 1.0f / sqrtf(fmaxf((float)h[t], 1.0f));
        }
        return;
    }
    __shared__ int fh[512], fcur[512];
    __shared__ int cl[KB];
    __shared__ int stage[ESCAP];
    __shared__ int sbeg;
    if (t < KB) cl[t] = cntD[B * KB + t];
    for (int i = t; i < 512; i += PTB) fh[i] = 0;
    if (w == 0) {
        int s = 0;
        for (int j = lane; j < B; j += 64) s += btot[j];
        for (int o = 32; o > 0; o >>= 1) s += __shfl_xor(s, o, 64);
        if (lane == 0) sbeg = s;
    }
    if (B == 0 && t == 128) row_ptr[NN] = NE;
    __syncthreads();
    int beg = sbeg;
    for (int r0 = 0; r0 < KB; r0 += 32) {
        int r = r0 + (w << 2) + (lane >> 4);
        if (r < KB) {
            int c = cl[r];
            const int* run = pbuf + ((size_t)B * KB + r) * CAPD;
            for (int k = lane & 15; k < c; k += 16) atomicAdd(&fh[run[k] >> 17], 1);
        }
    }
    __syncthreads();
    if (w == 0) {
        int v[8];
        int s = 0;
#pragma unroll
        for (int j = 0; j < 8; ++j) { v[j] = fh[lane * 8 + j]; s += v[j]; }
        int incl = s;
        for (int o = 1; o < 64; o <<= 1) {
            int u = __shfl_up(incl, o, 64);
            if (lane >= o) incl += u;
        }
        int run = incl - s;
#pragma unroll
        for (int j = 0; j < 8; ++j) {
            int bin = lane * 8 + j;
            fcur[bin] = run;
            int n = (B << 9) + bin;
            if (n < NN) {
                row_ptr[n] = beg + run;
                ndst[n] = 1.0f / sqrtf(fmaxf((float)v[j], 1.0f));
            }
            run += v[j];
        }
    }
    __syncthreads();
    for (int r0 = 0; r0 < KB; r0 += 32) {
        int r = r0 + (w << 2) + (lane >> 4);
        if (r < KB) {
            int c = cl[r];
            const int* run = pbuf + ((size_t)B * KB + r) * CAPD;
            for (int k = lane & 15; k < c; k += 16) {
                int v = run[k];
                int p = atomicAdd(&fcur[v >> 17], 1);
                stage[p] = v & 0x1FFFF;
            }
        }
    }
    __syncthreads();
    int cnt = btot[B];
    for (int i = t; i < cnt; i += PTB) esrc[beg + i] = stage[i];
}

// ---------------- K4 (fused): aggregate-1 + transform-2 ----------------
// Block = 256 threads / 64 nodes. Phase A: r10-proven aggregate (4 nodes/wave x 4
// passes, 8 chains/wave, bias1 + relu in regs) writing into the LDS xT tile
// (transposed + XOR-swizzled = tile_tf layout; 2-way max on writes). Phase B:
// r7-proven tile_tf compute -> t2 = fp16(nsrc*(h1@W2)). Deletes the 51.2MB
// h1 round-trip and one dispatch.
__global__ __launch_bounds__(256) void agg_tf_kernel(
    const _Float16* __restrict__ t, const int* __restrict__ row_ptr,
    const int* __restrict__ esrc, const float* __restrict__ nsrc,
    const float* __restrict__ ndst, const float* __restrict__ bias,
    const float* __restrict__ W, _Float16* __restrict__ out)
{
    __shared__ float xT[64 * 64];       // 16 KB
    int tid = threadIdx.x;
    int lane = tid & 63, wv = tid >> 6;     // 4 waves
    int tileBase = blockIdx.x * 64;
    int quad = lane >> 4;
    int l4 = lane & 15;
    int g = l4 >> 3, c = l4 & 7;
    float4 blo = *(const float4*)(bias + (c << 3));
    float4 bhi = *(const float4*)(bias + (c << 3) + 4);
#pragma unroll 1
    for (int pass = 0; pass < 4; ++pass) {
        int m = (wv << 4) + (pass << 2) + quad;     // node-in-tile 0..63
        int node = tileBase + m;
        float a0[8] = {0,0,0,0,0,0,0,0};
        float a1[8] = {0,0,0,0,0,0,0,0};
        float h[8];
        if (node < NN) {
            int beg = row_ptr[node], end = row_ptr[node + 1];
            int i = beg;
            for (; i + 4 <= end; i += 4) {
                int s0 = esrc[i + g];
                int s1 = esrc[i + 2 + g];
                float ns0 = nsrc[s0];
                float ns1 = nsrc[s1];
                h8v v0 = *(const h8v*)(t + (size_t)s0 * D + (c << 3));
                h8v v1 = *(const h8v*)(t + (size_t)s1 * D + (c << 3));
#pragma unroll
                for (int j = 0; j < 8; ++j) {
                    a0[j] += (float)v0[j] * ns0;
                    a1[j] += (float)v1[j] * ns1;
                }
            }
            for (; i < end; i += 2) {
                int e = i + g;
                if (e < end) {
                    int s = esrc[e];
                    float ns = nsrc[s];
                    h8v v = *(const h8v*)(t + (size_t)s * D + (c << 3));
#pragma unroll
                    for (int j = 0; j < 8; ++j) a0[j] += (float)v[j] * ns;
                }
            }
#pragma unroll
            for (int j = 0; j < 8; ++j) a0[j] += a1[j];
#pragma unroll
            for (int j = 0; j < 8; ++j) a0[j] += __shfl_xor(a0[j], 8, 64);
            float nd = ndst[node];
            h[0] = fmaxf(a0[0] * nd + blo.x, 0.f); h[1] = fmaxf(a0[1] * nd + blo.y, 0.f);
            h[2] = fmaxf(a0[2] * nd + blo.z, 0.f); h[3] = fmaxf(a0[3] * nd + blo.w, 0.f);
            h[4] = fmaxf(a0[4] * nd + bhi.x, 0.f); h[5] = fmaxf(a0[5] * nd + bhi.y, 0.f);
            h[6] = fmaxf(a0[6] * nd + bhi.z, 0.f); h[7] = fmaxf(a0[7] * nd + bhi.w, 0.f);
        } else {
#pragma unroll
            for (int j = 0; j < 8; ++j) h[j] = 0.f;
        }
        // LDS write: g=0 lanes write k=c*8+0..3, g=1 lanes k=c*8+4..7 (2-way max)
#pragma unroll
        for (int j = 0; j < 4; ++j) {
            int k = (c << 3) + (g << 2) + j;
            xT[k * 64 + (m ^ (k & 60))] = h[(g << 2) + j];
        }
    }
    __syncthreads();
    // ---- phase B: tile_tf compute (proven mapping), scale = nsrc ----
    int m0 = (lane >> 2) << 2;
    int nc = (wv << 4) + ((lane & 3) << 2);
    float4 b0 = {0,0,0,0}, b1_ = {0,0,0,0}, b2_ = {0,0,0,0}, b3 = {0,0,0,0};
#pragma unroll 8
    for (int k = 0; k < 64; ++k) {
        int P = k & 60;
        float4 xa = *(const float4*)(xT + k * 64 + (m0 ^ P));
        float4 wv4 = *(const float4*)(W + k * D + nc);
        b0.x += xa.x * wv4.x; b0.y += xa.x * wv4.y; b0.z += xa.x * wv4.z; b0.w += xa.x * wv4.w;
        b1_.x += xa.y * wv4.x; b1_.y += xa.y * wv4.y; b1_.z += xa.y * wv4.z; b1_.w += xa.y * wv4.w;
        b2_.x += xa.z * wv4.x; b2_.y += xa.z * wv4.y; b2_.z += xa.z * wv4.z; b2_.w += xa.z * wv4.w;
        b3.x += xa.w * wv4.x; b3.y += xa.w * wv4.y; b3.z += xa.w * wv4.z; b3.w += xa.w * wv4.w;
    }
    float4 acc[4] = {b0, b1_, b2_, b3};
#pragma unroll
    for (int j = 0; j < 4; ++j) {
        int node = tileBase + m0 + j;
        if (node < NN) {
            float sc = nsrc[node];
            h4v o;
            o[0] = (_Float16)(acc[j].x * sc); o[1] = (_Float16)(acc[j].y * sc);
            o[2] = (_Float16)(acc[j].z * sc); o[3] = (_Float16)(acc[j].w * sc);
            *(h4v*)(out + (size_t)node * D + nc) = o;
        }
    }
}

// ---------------- K5: aggregation layer 2 (r10-proven; no relu, no nsrc) --------------
template<int RELU, int USE_NSRC>
__global__ __launch_bounds__(256) void aggregate_kernel(const _Float16* __restrict__ t,
                                                        const int* __restrict__ row_ptr,
                                                        const int* __restrict__ esrc,
                                                        const float* __restrict__ nsrc,
                                                        const float* __restrict__ ndst,
                                                        const float* __restrict__ bias,
                                                        float* __restrict__ out) {
    int wid = (blockIdx.x * 256 + threadIdx.x) >> 6;
    int lane = threadIdx.x & 63;
    int quad = lane >> 4;
    int l4 = lane & 15;
    int g = l4 >> 3, c = l4 & 7;
    int node = wid * 4 + quad;
    if (node >= NN) return;
    int beg = row_ptr[node], end = row_ptr[node + 1];
    float a0[8] = {0,0,0,0,0,0,0,0};
    float a1[8] = {0,0,0,0,0,0,0,0};
    int i = beg;
    for (; i + 4 <= end; i += 4) {
        int s0 = esrc[i + g];
        int s1 = esrc[i + 2 + g];
        float ns0 = USE_NSRC ? nsrc[s0] : 1.0f;
        float ns1 = USE_NSRC ? nsrc[s1] : 1.0f;
        h8v v0 = *(const h8v*)(t + (size_t)s0 * D + (c << 3));
        h8v v1 = *(const h8v*)(t + (size_t)s1 * D + (c << 3));
#pragma unroll
        for (int j = 0; j < 8; ++j) {
            if (USE_NSRC) { a0[j] += (float)v0[j] * ns0; a1[j] += (float)v1[j] * ns1; }
            else          { a0[j] += (float)v0[j];       a1[j] += (float)v1[j]; }
        }
    }
    for (; i < end; i += 2) {
        int e = i + g;
        if (e < end) {
            int s = esrc[e];
            float ns = USE_NSRC ? nsrc[s] : 1.0f;
            h8v v = *(const h8v*)(t + (size_t)s * D + (c << 3));
#pragma unroll
            for (int j = 0; j < 8; ++j) {
                if (USE_NSRC) a0[j] += (float)v[j] * ns;
                else          a0[j] += (float)v[j];
            }
        }
    }
#pragma unroll
    for (int j = 0; j < 8; ++j) a0[j] += a1[j];
#pragma unroll
    for (int j = 0; j < 8; ++j) {
        a0[j] += __shfl_xor(a0[j], 8, 64);
    }
    float nd = ndst[node];
    float4 blo = *(const float4*)(bias + (c << 3));
    float4 bhi = *(const float4*)(bias + (c << 3) + 4);
    float h[8];
    h[0] = a0[0] * nd + blo.x; h[1] = a0[1] * nd + blo.y;
    h[2] = a0[2] * nd + blo.z; h[3] = a0[3] * nd + blo.w;
    h[4] = a0[4] * nd + bhi.x; h[5] = a0[5] * nd + bhi.y;
    h[6] = a0[6] * nd + bhi.z; h[7] = a0[7] * nd + bhi.w;
    if (RELU) {
#pragma unroll
        for (int j = 0; j < 8; ++j) h[j] = fmaxf(h[j], 0.f);
    }
    if (g == 0) {
        float4 o0 = {h[0], h[1], h[2], h[3]};
        float4 o1 = {h[4], h[5], h[6], h[7]};
        *(float4*)(out + (size_t)node * D + (c << 3)) = o0;
        *(float4*)(out + (size_t)node * D + (c << 3) + 4) = o1;
    }
}

// ---------------- launcher ----------------
extern "C" void kernel_launch(void* const* d_in, const int* in_sizes, int n_in,
                              void* d_out, int out_size, void* d_ws, size_t ws_size,
                              hipStream_t stream) {
    const float* x  = (const float*)d_in[0];
    const int* src  = (const int*)d_in[1];
    const int* dst  = (const int*)d_in[2];
    const float* W1 = (const float*)d_in[3];
    const float* b1 = (const float*)d_in[4];
    const float* W2 = (const float*)d_in[5];
    const float* b2 = (const float*)d_in[6];
    float* out = (float*)d_out;

    size_t off = 0;
    auto alloc = [&](size_t bytes) -> void* {
        void* p = (char*)d_ws + off;
        off += (bytes + 255) & ~(size_t)255;
        return p;
    };
    int* row_ptr  = (int*)alloc((size_t)(NN + 1) * 4);
    float* nsrc   = (float*)alloc((size_t)NN * 4);
    float* ndst   = (float*)alloc((size_t)NN * 4);
    int* btot     = (int*)alloc((size_t)256 * 4);
    int* cntD     = (int*)alloc((size_t)NBD * KB * 4);           // 392 KB
    int* cntS     = (int*)alloc((size_t)NBS * KB * 4);           // 782 KB
    int* esrc     = (int*)alloc((size_t)NE * 4);                 // 6.4 MB
    _Float16* t_h = (_Float16*)alloc((size_t)NN * D * 2);        // 12.8 MB
    // scratch region: pbuf 17.2MB + qloc 7.0MB = 24.2MB; after finalize it is dead
    // and t2 (12.8MB fp16) aliases its start.
    char* scratch = (char*)alloc((size_t)NBD * KB * CAPD * 4 + (size_t)NBS * KB * CAPS);
    (void)ws_size;
    int* pbuf = (int*)scratch;
    unsigned char* qloc = (unsigned char*)(pbuf + (size_t)NBD * KB * CAPD);
    _Float16* t2 = (_Float16*)scratch;

    partition_tf1_kernel<<<KB + TFB, PTB, 0, stream>>>(src, dst, cntD, cntS,
                                                       pbuf, qloc, x, W1, t_h);
    scan1_kernel<<<NBD, 256, 0, stream>>>(cntD, btot);
    finalize_kernel<<<NBD + NBS, PTB, 0, stream>>>(pbuf, qloc, cntD, cntS, btot,
                                                   row_ptr, nsrc, ndst, esrc);

    agg_tf_kernel<<<AGTB, 256, 0, stream>>>(t_h, row_ptr, esrc, nsrc, ndst, b1, W2, t2);
    aggregate_kernel<0, 0><<<6250, 256, 0, stream>>>(t2, row_ptr, esrc, nsrc, ndst, b2, out);
}